// Round 15
// baseline (247.108 us; speedup 1.0000x reference)
//
#include <hip/hip_runtime.h>
#include <math.h>

typedef __attribute__((ext_vector_type(4))) float f32x4;
typedef __attribute__((ext_vector_type(16))) float f32x16;
typedef __attribute__((ext_vector_type(8))) __bf16 bf16x8;
typedef __attribute__((ext_vector_type(4))) unsigned int u32x4;
typedef __attribute__((ext_vector_type(4))) unsigned short u16x4;

#define DEVI __device__ __forceinline__

// B=4, S=2048, E=1024, H=16, D=64, M=B*S=8192
constexpr size_t WS_WB  = 0;
constexpr size_t WS_COS = 4ull * 1024 * 1024 * 2;
constexpr size_t WS_SIN = WS_COS + 2048 * 32 * 4;
constexpr size_t WS_QH  = WS_SIN + 2048 * 32 * 4;
constexpr size_t WS_KH  = WS_QH + 64ull * 2048 * 64 * 2;
constexpr size_t WS_VT  = WS_KH + 64ull * 2048 * 64 * 2;
constexpr size_t WS_AO  = WS_VT + 64ull * 64 * 2048 * 2;  // AO bf16 [8192][1024]

DEVI unsigned short f2bf(float x) {
  union { float f; unsigned int u; } v; v.f = x;
  unsigned int r = v.u + 0x7fffu + ((v.u >> 16) & 1u);  // RNE
  return (unsigned short)(r >> 16);
}

DEVI unsigned cvtpk(float a, float b) {
  union { __bf16 h[2]; unsigned u; } x;
  x.h[0] = (__bf16)a; x.h[1] = (__bf16)b;
  return x.u;
}

// async global->LDS DMA, 16B/lane; dest = wave-uniform base, HW adds lane*16
DEVI void ld_lds16(const void* g, void* l) {
  __builtin_amdgcn_global_load_lds((const __attribute__((address_space(1))) void*)g,
                                   (__attribute__((address_space(3))) void*)l, 16, 0, 0);
}

// ---------------- prep: weights fp32->bf16 (y<4) + RoPE tables (y==4) ----------------
__global__ __launch_bounds__(256) void prep(const float* __restrict__ w0,
                                            const float* __restrict__ w1,
                                            const float* __restrict__ w2,
                                            const float* __restrict__ w3,
                                            unsigned short* __restrict__ out,
                                            float* __restrict__ cosT,
                                            float* __restrict__ sinT) {
  if (blockIdx.y == 4) {
    if (blockIdx.x >= 256) return;
    int idx = blockIdx.x * 256 + threadIdx.x;  // 65536 = 2048*32
    int s = idx >> 5, i = idx & 31;
    double ang = (double)s * pow(10000.0, -(double)i / 32.0);
    cosT[idx] = (float)cos(ang);
    sinT[idx] = (float)sin(ang);
    return;
  }
  const float* w = blockIdx.y == 0 ? w0 : blockIdx.y == 1 ? w1 : blockIdx.y == 2 ? w2 : w3;
  int i = (blockIdx.x * 256 + threadIdx.x) * 4;
  f32x4 v = *(const f32x4*)(w + i);
  u16x4 o;
  o.x = f2bf(v.x); o.y = f2bf(v.y); o.z = f2bf(v.z); o.w = f2bf(v.w);
  *(u16x4*)(out + (size_t)blockIdx.y * 1048576 + i) = o;
}

// ---------------- 128x128x(K=1024) GEMM, double-buffered global_load_lds (R5-proven) ----------------
// A: [M][1024] f32 (AF32) or bf16. W: bf16 [N][1024]. Pre-swizzled source + linear DMA dest;
// ds_read applies same XOR. Race-free: end-of-iter vmcnt(0)+barrier fences all reads of cur
// before the NEXT iter's stage overwrites the other buffer (readers of that buffer were
// fenced one barrier earlier). Measured ~31 us/GEMM as part of R5's 231.9 total.
// EPI: 0=Q(rope,scale incl log2e), 1=K(rope), 2=V(transposed store), 3=out(f32+bias)
template <int EPI, bool AF32>
__global__ __launch_bounds__(256) void gemm_mha(const void* __restrict__ Av,
                                                const unsigned short* __restrict__ W,
                                                void* __restrict__ outp,
                                                const float* __restrict__ cosT,
                                                const float* __restrict__ sinT,
                                                const float* __restrict__ bo) {
  __shared__ __align__(16) char AsRaw[2][AF32 ? 16384 : 8192];  // [128][32] f32 / bf16
  __shared__ __align__(16) unsigned short Bs[2][4096];          // [128][32] bf16

  const int tid = threadIdx.x;
  const int lane = tid & 63;
  const int wave = tid >> 6;
  const int flat = blockIdx.x;
  const int wgid = (flat & 7) * 64 + (flat >> 3);  // XCD chunk-swizzle
  const int m0 = (wgid >> 3) * 128;
  const int n0 = (wgid & 7) * 128;
  const int wm = (wave >> 1) * 64;
  const int wn = (wave & 1) * 64;
  const int hi2 = lane >> 4;

  const float* Af = (const float*)Av;
  const unsigned short* Ab = (const unsigned short*)Av;

  f32x4 acc[4][4] = {};

  auto stage = [&](int buf, int kt) {
    const int k0 = kt * 32;
    if constexpr (AF32) {
      float* AsF = (float*)AsRaw[buf];
#pragma unroll
      for (int i = 0; i < 4; ++i) {  // f32 rows 128B: swz u^(row&7) on 16B units
        int g = i * 256 + tid;
        int row = g >> 3, u = g & 7;
        ld_lds16(Af + (size_t)(m0 + row) * 1024 + k0 + ((u ^ (row & 7)) << 2),
                 AsF + ((i * 256 + wave * 64) << 2));
      }
    } else {
      unsigned short* Asb = (unsigned short*)AsRaw[buf];
#pragma unroll
      for (int i = 0; i < 2; ++i) {  // bf16 rows 64B: swz u^((row>>1)&3)
        int g = i * 256 + tid;
        int row = g >> 2, u = g & 3;
        ld_lds16(Ab + (size_t)(m0 + row) * 1024 + k0 + ((u ^ ((row >> 1) & 3)) << 3),
                 Asb + ((i * 256 + wave * 64) << 3));
      }
    }
#pragma unroll
    for (int i = 0; i < 2; ++i) {
      int g = i * 256 + tid;
      int row = g >> 2, u = g & 3;
      ld_lds16(W + (size_t)(n0 + row) * 1024 + k0 + ((u ^ ((row >> 1) & 3)) << 3),
               Bs[buf] + ((i * 256 + wave * 64) << 3));
    }
  };

  stage(0, 0);
  asm volatile("s_waitcnt vmcnt(0)" ::: "memory");
  __builtin_amdgcn_s_barrier();

  for (int kt = 0; kt < 32; ++kt) {
    const int cur = kt & 1;
    if (kt < 31) stage(cur ^ 1, kt + 1);  // next tile's DMA issued; lands during compute

    const float* AsF = (const float*)AsRaw[cur];
    const unsigned short* Asb = (const unsigned short*)AsRaw[cur];
    bf16x8 af[4], bfr[4];
#pragma unroll
    for (int x = 0; x < 4; ++x) {
      int row = wm + x * 16 + (lane & 15);
      if constexpr (AF32) {
        int swz = row & 7;
        f32x4 a0 = *(const f32x4*)(AsF + row * 32 + (((hi2 * 2) ^ swz) << 2));
        f32x4 a1 = *(const f32x4*)(AsF + row * 32 + (((hi2 * 2 + 1) ^ swz) << 2));
        union { u32x4 u; bf16x8 v; } f;
        f.u.x = cvtpk(a0.x, a0.y); f.u.y = cvtpk(a0.z, a0.w);
        f.u.z = cvtpk(a1.x, a1.y); f.u.w = cvtpk(a1.z, a1.w);
        af[x] = f.v;
      } else {
        af[x] = *(const bf16x8*)(Asb + row * 32 + ((hi2 ^ ((row >> 1) & 3)) << 3));
      }
      int brow = wn + x * 16 + (lane & 15);
      bfr[x] = *(const bf16x8*)(Bs[cur] + brow * 32 + ((hi2 ^ ((brow >> 1) & 3)) << 3));
    }
#pragma unroll
    for (int mi = 0; mi < 4; ++mi)
#pragma unroll
      for (int ni = 0; ni < 4; ++ni)
        acc[mi][ni] = __builtin_amdgcn_mfma_f32_16x16x32_bf16(af[mi], bfr[ni], acc[mi][ni], 0, 0, 0);

    if (kt < 31) {
      asm volatile("s_waitcnt vmcnt(0)" ::: "memory");  // next tile landed during compute
      __builtin_amdgcn_s_barrier();                     // all reads of cur done block-wide
    }
  }

  const int b = m0 >> 11;
  const int sbase = (m0 & 2047) + wm + ((lane >> 4) << 2);

  if constexpr (EPI == 0 || EPI == 1) {
    unsigned short* dst = (unsigned short*)outp;
    const float scale = EPI == 0 ? 0.18033688011112042f : 1.0f;  // (1/8)*log2e on Q
#pragma unroll
    for (int ni = 0; ni < 4; ++ni) {
      int n = n0 + wn + ni * 16 + (lane & 15);
      int h = n >> 6, d = n & 63, fi = d >> 1;
      size_t base = (size_t)(b * 16 + h) * 131072 + d;
#pragma unroll
      for (int mi = 0; mi < 4; ++mi) {
#pragma unroll
        for (int r = 0; r < 4; ++r) {
          int s = sbase + mi * 16 + r;
          float v = acc[mi][ni][r];
          float p = __shfl_xor(v, 1);
          float c = cosT[(s << 5) + fi], sn = sinT[(s << 5) + fi];
          float ov = (d & 1) ? (p * sn + v * c) : (v * c - p * sn);
          dst[base + (size_t)s * 64] = f2bf(ov * scale);
        }
      }
    }
  } else if constexpr (EPI == 2) {
    unsigned short* dst = (unsigned short*)outp;  // Vt [bh][d][s]
#pragma unroll
    for (int ni = 0; ni < 4; ++ni) {
      int n = n0 + wn + ni * 16 + (lane & 15);
      int h = n >> 6, d = n & 63;
#pragma unroll
      for (int mi = 0; mi < 4; ++mi) {
        u16x4 pk;
        pk.x = f2bf(acc[mi][ni][0]); pk.y = f2bf(acc[mi][ni][1]);
        pk.z = f2bf(acc[mi][ni][2]); pk.w = f2bf(acc[mi][ni][3]);
        int s = sbase + mi * 16;
        *(u16x4*)(dst + ((size_t)(b * 16 + h) * 64 + d) * 2048 + s) = pk;
      }
    }
  } else {
    float* dst = (float*)outp;
#pragma unroll
    for (int ni = 0; ni < 4; ++ni) {
      int n = n0 + wn + ni * 16 + (lane & 15);
      float bias = bo[n];
#pragma unroll
      for (int mi = 0; mi < 4; ++mi)
#pragma unroll
        for (int r = 0; r < 4; ++r) {
          int m = m0 + wm + mi * 16 + ((lane >> 4) << 2) + r;
          dst[(size_t)m * 1024 + n] = acc[mi][ni][r] + bias;
        }
    }
  }
}

// exp2 + sum + pack one 64-key S^T pair -> PV A-fragments; returns lane-partial sum
DEVI float tile_sm(f32x16& s0, f32x16& s1, bf16x8* pa) {
  float a0 = 0.f, a1 = 0.f, a2 = 0.f, a3 = 0.f;
#pragma unroll
  for (int r = 0; r < 16; r += 4) {
    s0[r] = __builtin_amdgcn_exp2f(s0[r]);         a0 += s0[r];
    s0[r + 1] = __builtin_amdgcn_exp2f(s0[r + 1]); a1 += s0[r + 1];
    s0[r + 2] = __builtin_amdgcn_exp2f(s0[r + 2]); a2 += s0[r + 2];
    s0[r + 3] = __builtin_amdgcn_exp2f(s0[r + 3]); a3 += s0[r + 3];
  }
#pragma unroll
  for (int r = 0; r < 16; r += 4) {
    s1[r] = __builtin_amdgcn_exp2f(s1[r]);         a0 += s1[r];
    s1[r + 1] = __builtin_amdgcn_exp2f(s1[r + 1]); a1 += s1[r + 1];
    s1[r + 2] = __builtin_amdgcn_exp2f(s1[r + 2]); a2 += s1[r + 2];
    s1[r + 3] = __builtin_amdgcn_exp2f(s1[r + 3]); a3 += s1[r + 3];
  }
#pragma unroll
  for (int blk = 0; blk < 2; ++blk) {
    const f32x16& s = blk ? s1 : s0;
#pragma unroll
    for (int half = 0; half < 2; ++half) {
      int o = half * 8;
      unsigned u0 = cvtpk(s[o + 0], s[o + 1]);
      unsigned u1 = cvtpk(s[o + 2], s[o + 3]);
      unsigned u2 = cvtpk(s[o + 4], s[o + 5]);
      unsigned u3 = cvtpk(s[o + 6], s[o + 7]);
      auto r02 = __builtin_amdgcn_permlane32_swap(u0, u2, false, false);
      auto r13 = __builtin_amdgcn_permlane32_swap(u1, u3, false, false);
      union { u32x4 u; bf16x8 v; } f;
      f.u.x = r02[0]; f.u.y = r13[0]; f.u.z = r02[1]; f.u.w = r13[1];
      pa[blk * 2 + half] = f.v;
    }
  }
  return (a0 + a1) + (a2 + a3);
}

// ---------------- flash attention: KVBLK=64, 64 q/wave, race-free two-barrier rounds (R14) ----------------
__global__ __launch_bounds__(256, 2) void attn_kernel(const unsigned short* __restrict__ Qh,
                                                      const unsigned short* __restrict__ Kh,
                                                      const unsigned short* __restrict__ Vt,
                                                      unsigned short* __restrict__ AOb) {
  __shared__ __align__(16) unsigned short SM[4][4096];  // K0,V0,K1,V1

  const int tid = threadIdx.x, lane = tid & 63, wave = tid >> 6;
  const int lid = blockIdx.x;  // 0..511
  const int xcd = lid & 7, slot = lid >> 3;
  const int bh = xcd * 8 + (slot >> 3);  // 8 bh per XCD
  const int qb = slot & 7;
  const int q0 = qb * 256 + wave * 64;
  const int lq = lane & 31, hi = lane >> 5;

  const unsigned short* Qgb = Qh + (size_t)bh * 131072;
  const unsigned short* Kgb = Kh + (size_t)bh * 131072;
  const unsigned short* Vgb = Vt + (size_t)bh * 131072;

  bf16x8 qfa[4], qfb[4];
#pragma unroll
  for (int st = 0; st < 4; ++st) {
    qfa[st] = *(const bf16x8*)(Qgb + (size_t)(q0 + lq) * 64 + st * 16 + hi * 8);
    qfb[st] = *(const bf16x8*)(Qgb + (size_t)(q0 + 32 + lq) * 64 + st * 16 + hi * 8);
  }

  const int r0 = wave * 8 + (lane >> 3);
  const int u0 = lane & 7;
  const int sw = (u0 ^ (r0 & 7)) << 3;
  const unsigned short* kp0 = Kgb + r0 * 64 + sw;
  const unsigned short* kp1 = Kgb + (32 + r0) * 64 + sw;
  const unsigned short* vp0 = Vgb + (size_t)r0 * 2048 + sw;
  const unsigned short* vp1 = Vgb + (size_t)(32 + r0) * 2048 + sw;
  const int d0 = wave * 512, d1 = 2048 + wave * 512;

  auto stage = [&](int buf, int kt) {
    unsigned short* Kd = SM[buf * 2];
    unsigned short* Vd = SM[buf * 2 + 1];
    ld_lds16(kp0 + kt * 4096, Kd + d0);
    ld_lds16(kp1 + kt * 4096, Kd + d1);
    ld_lds16(vp0 + kt * 64, Vd + d0);
    ld_lds16(vp1 + kt * 64, Vd + d1);
  };
  auto frag = [&](const unsigned short* base, int row, int c) -> bf16x8 {
    return *(const bf16x8*)(base + row * 64 + (((c ^ (row & 7)) << 3)));
  };

  f32x16 o0a = {}, o1a = {}, o0b = {}, o1b = {};
  float lsA = 0.f, lsB = 0.f;

  stage(0, 0);

  for (int kt = 0; kt < 32; ++kt) {
    const int cur = kt & 1;
    if (kt < 31) {
      stage(cur ^ 1, kt + 1);
      asm volatile("s_waitcnt vmcnt(4)" ::: "memory");  // tile kt landed; kt+1 in flight
    } else {
      asm volatile("s_waitcnt vmcnt(0)" ::: "memory");
    }
    __builtin_amdgcn_s_barrier();  // barrier1: all waves' tile-kt DMA visible
    const unsigned short* Kc = SM[cur * 2];
    const unsigned short* Vc = SM[cur * 2 + 1];

    // all frag reads up front: V-read latency hides under QK+SM
    bf16x8 kf0[4], kf1[4], vf0[4], vf1[4];
#pragma unroll
    for (int st = 0; st < 4; ++st) {
      kf0[st] = frag(Kc, lq, st * 2 + hi);
      kf1[st] = frag(Kc, 32 + lq, st * 2 + hi);
      vf0[st] = frag(Vc, lq, st * 2 + hi);
      vf1[st] = frag(Vc, 32 + lq, st * 2 + hi);
    }

    f32x16 s0a = {}, s1a = {}, s0b = {}, s1b = {};
#pragma unroll
    for (int st = 0; st < 4; ++st) {
      s0a = __builtin_amdgcn_mfma_f32_32x32x16_bf16(kf0[st], qfa[st], s0a, 0, 0, 0);
      s1a = __builtin_amdgcn_mfma_f32_32x32x16_bf16(kf1[st], qfa[st], s1a, 0, 0, 0);
      s0b = __builtin_amdgcn_mfma_f32_32x32x16_bf16(kf0[st], qfb[st], s0b, 0, 0, 0);
      s1b = __builtin_amdgcn_mfma_f32_32x32x16_bf16(kf1[st], qfb[st], s1b, 0, 0, 0);
    }

    bf16x8 paA[4], paB[4];
    lsA += tile_sm(s0a, s1a, paA);
    lsB += tile_sm(s0b, s1b, paB);

#pragma unroll
    for (int kc = 0; kc < 4; ++kc) {
      o0a = __builtin_amdgcn_mfma_f32_32x32x16_bf16(paA[kc], vf0[kc], o0a, 0, 0, 0);
      o1a = __builtin_amdgcn_mfma_f32_32x32x16_bf16(paA[kc], vf1[kc], o1a, 0, 0, 0);
      o0b = __builtin_amdgcn_mfma_f32_32x32x16_bf16(paB[kc], vf0[kc], o0b, 0, 0, 0);
      o1b = __builtin_amdgcn_mfma_f32_32x32x16_bf16(paB[kc], vf1[kc], o1b, 0, 0, 0);
    }

    if (kt < 31) {
      __builtin_amdgcn_s_barrier();  // barrier2: reads of cur done before next round's
    }                                // stage overwrites it (WAR fix)
  }

  lsA += __shfl_xor(lsA, 32);
  lsB += __shfl_xor(lsB, 32);
  const int b = bh >> 4, h = bh & 15;
#pragma unroll
  for (int r = 0; r < 16; ++r) {
    int row = (r & 3) + 8 * (r >> 2) + 4 * hi;
    float ia = 1.0f / __shfl(lsA, row);
    float ib = 1.0f / __shfl(lsB, row);
    unsigned short* da = AOb + (size_t)(b * 2048 + q0 + row) * 1024 + h * 64;
    unsigned short* db = AOb + (size_t)(b * 2048 + q0 + 32 + row) * 1024 + h * 64;
    da[lq] = f2bf(o0a[r] * ia);
    da[32 + lq] = f2bf(o1a[r] * ia);
    db[lq] = f2bf(o0b[r] * ib);
    db[32 + lq] = f2bf(o1b[r] * ib);
  }
}

extern "C" void kernel_launch(void* const* d_in, const int* in_sizes, int n_in,
                              void* d_out, int out_size, void* d_ws, size_t ws_size,
                              hipStream_t stream) {
  const float* query = (const float*)d_in[0];
  const float* key = (const float*)d_in[1];
  const float* value = (const float*)d_in[2];
  const float* Wq = (const float*)d_in[3];
  const float* Wk = (const float*)d_in[4];
  const float* Wv = (const float*)d_in[5];
  const float* Wo = (const float*)d_in[6];
  const float* bo = (const float*)d_in[7];

  char* ws = (char*)d_ws;
  unsigned short* Wb = (unsigned short*)(ws + WS_WB);
  float* cosT = (float*)(ws + WS_COS);
  float* sinT = (float*)(ws + WS_SIN);
  unsigned short* Qh = (unsigned short*)(ws + WS_QH);
  unsigned short* Kh = (unsigned short*)(ws + WS_KH);
  unsigned short* Vt = (unsigned short*)(ws + WS_VT);
  unsigned short* AOb = (unsigned short*)(ws + WS_AO);

  prep<<<dim3(1024, 5), 256, 0, stream>>>(Wq, Wk, Wv, Wo, Wb, cosT, sinT);
  gemm_mha<0, true><<<512, 256, 0, stream>>>(query, Wb, Qh, cosT, sinT, nullptr);
  gemm_mha<1, true><<<512, 256, 0, stream>>>(key, Wb + 1048576, Kh, cosT, sinT, nullptr);
  gemm_mha<2, true><<<512, 256, 0, stream>>>(value, Wb + 2097152, Vt, cosT, sinT, nullptr);
  attn_kernel<<<512, 256, 0, stream>>>(Qh, Kh, Vt, AOb);
  gemm_mha<3, false><<<512, 256, 0, stream>>>(AOb, Wb + 3145728, d_out, cosT, sinT, bo);
}

// Round 16
// 216.388 us; speedup vs baseline: 1.1420x; 1.1420x over previous
//
#include <hip/hip_runtime.h>
#include <math.h>

typedef __attribute__((ext_vector_type(4))) float f32x4;
typedef __attribute__((ext_vector_type(16))) float f32x16;
typedef __attribute__((ext_vector_type(8))) __bf16 bf16x8;
typedef __attribute__((ext_vector_type(4))) unsigned int u32x4;
typedef __attribute__((ext_vector_type(4))) unsigned short u16x4;

#define DEVI __device__ __forceinline__

// B=4, S=2048, E=1024, H=16, D=64, M=B*S=8192
constexpr size_t WS_WB  = 0;
constexpr size_t WS_COS = 4ull * 1024 * 1024 * 2;
constexpr size_t WS_SIN = WS_COS + 2048 * 32 * 4;
constexpr size_t WS_QH  = WS_SIN + 2048 * 32 * 4;
constexpr size_t WS_KH  = WS_QH + 64ull * 2048 * 64 * 2;
constexpr size_t WS_VT  = WS_KH + 64ull * 2048 * 64 * 2;
constexpr size_t WS_AO  = WS_VT + 64ull * 64 * 2048 * 2;  // AO bf16 [8192][1024]

DEVI unsigned short f2bf(float x) {
  union { float f; unsigned int u; } v; v.f = x;
  unsigned int r = v.u + 0x7fffu + ((v.u >> 16) & 1u);  // RNE
  return (unsigned short)(r >> 16);
}

DEVI unsigned cvtpk(float a, float b) {
  union { __bf16 h[2]; unsigned u; } x;
  x.h[0] = (__bf16)a; x.h[1] = (__bf16)b;
  return x.u;
}

// async global->LDS DMA, 16B/lane; dest = wave-uniform base, HW adds lane*16
DEVI void ld_lds16(const void* g, void* l) {
  __builtin_amdgcn_global_load_lds((const __attribute__((address_space(1))) void*)g,
                                   (__attribute__((address_space(3))) void*)l, 16, 0, 0);
}

// ---------------- prep: weights fp32->bf16 (y<4) + RoPE tables (y==4) ----------------
__global__ __launch_bounds__(256) void prep(const float* __restrict__ w0,
                                            const float* __restrict__ w1,
                                            const float* __restrict__ w2,
                                            const float* __restrict__ w3,
                                            unsigned short* __restrict__ out,
                                            float* __restrict__ cosT,
                                            float* __restrict__ sinT) {
  if (blockIdx.y == 4) {
    if (blockIdx.x >= 256) return;
    int idx = blockIdx.x * 256 + threadIdx.x;  // 65536 = 2048*32
    int s = idx >> 5, i = idx & 31;
    double ang = (double)s * pow(10000.0, -(double)i / 32.0);
    cosT[idx] = (float)cos(ang);
    sinT[idx] = (float)sin(ang);
    return;
  }
  const float* w = blockIdx.y == 0 ? w0 : blockIdx.y == 1 ? w1 : blockIdx.y == 2 ? w2 : w3;
  int i = (blockIdx.x * 256 + threadIdx.x) * 4;
  f32x4 v = *(const f32x4*)(w + i);
  u16x4 o;
  o.x = f2bf(v.x); o.y = f2bf(v.y); o.z = f2bf(v.z); o.w = f2bf(v.w);
  *(u16x4*)(out + (size_t)blockIdx.y * 1048576 + i) = o;
}

// ---------------- merged QKV GEMM: grid (512, 3), y selects matrix (best-verified) ----------------
// Single-buffer LDS; the 3 GEMMs' waves interleave across y -> tail overlap beats
// separate dbuf launches (R15 A/B: merged 84 us vs separate 115 us for the three).
__global__ __launch_bounds__(256) void gemm_qkv(const float* __restrict__ Aq,
                                                const float* __restrict__ Ak,
                                                const float* __restrict__ Av,
                                                const unsigned short* __restrict__ Wb,
                                                unsigned short* __restrict__ Qh,
                                                unsigned short* __restrict__ Kh,
                                                unsigned short* __restrict__ Vt,
                                                const float* __restrict__ cosT,
                                                const float* __restrict__ sinT) {
  __shared__ __align__(16) float AsF[128 * 32];            // [128][32] f32
  __shared__ __align__(16) unsigned short Bs[128 * 32];    // [128][32] bf16

  const int mat = blockIdx.y;  // 0=Q 1=K 2=V
  const float* A = mat == 0 ? Aq : mat == 1 ? Ak : Av;
  const unsigned short* W = Wb + (size_t)mat * 1048576;

  const int tid = threadIdx.x;
  const int lane = tid & 63;
  const int wave = tid >> 6;
  const int flat = blockIdx.x;
  const int wgid = (flat & 7) * 64 + (flat >> 3);  // XCD chunk-swizzle
  const int m0 = (wgid >> 3) * 128;
  const int n0 = (wgid & 7) * 128;
  const int wm = (wave >> 1) * 64;
  const int wn = (wave & 1) * 64;
  const int hi2 = lane >> 4;

  f32x4 acc[4][4] = {};

  for (int kt = 0; kt < 32; ++kt) {
    const int k0 = kt * 32;
#pragma unroll
    for (int i = 0; i < 4; ++i) {
      int g = i * 256 + tid;
      int row = g >> 3, u = g & 7;
      ld_lds16(A + (size_t)(m0 + row) * 1024 + k0 + ((u ^ (row & 7)) << 2),
               AsF + ((i * 256 + wave * 64) << 2));
    }
#pragma unroll
    for (int i = 0; i < 2; ++i) {
      int g = i * 256 + tid;
      int row = g >> 2, u = g & 3;
      ld_lds16(W + (size_t)(n0 + row) * 1024 + k0 + ((u ^ ((row >> 1) & 3)) << 3),
               Bs + ((i * 256 + wave * 64) << 3));
    }
    __syncthreads();  // drain DMA + all waves' prior reads done

    bf16x8 af[4], bfr[4];
#pragma unroll
    for (int x = 0; x < 4; ++x) {
      int row = wm + x * 16 + (lane & 15);
      int swz = row & 7;
      f32x4 a0 = *(const f32x4*)(AsF + row * 32 + (((hi2 * 2) ^ swz) << 2));
      f32x4 a1 = *(const f32x4*)(AsF + row * 32 + (((hi2 * 2 + 1) ^ swz) << 2));
      union { u32x4 u; bf16x8 v; } f;
      f.u.x = cvtpk(a0.x, a0.y); f.u.y = cvtpk(a0.z, a0.w);
      f.u.z = cvtpk(a1.x, a1.y); f.u.w = cvtpk(a1.z, a1.w);
      af[x] = f.v;
      int brow = wn + x * 16 + (lane & 15);
      bfr[x] = *(const bf16x8*)(Bs + brow * 32 + ((hi2 ^ ((brow >> 1) & 3)) << 3));
    }
#pragma unroll
    for (int mi = 0; mi < 4; ++mi)
#pragma unroll
      for (int ni = 0; ni < 4; ++ni)
        acc[mi][ni] = __builtin_amdgcn_mfma_f32_16x16x32_bf16(af[mi], bfr[ni], acc[mi][ni], 0, 0, 0);
    __syncthreads();  // all reads done before next DMA overwrite
  }

  const int b = m0 >> 11;
  const int sbase = (m0 & 2047) + wm + ((lane >> 4) << 2);

  if (mat < 2) {  // Q/K: RoPE + bf16 store [bh][s][d]; Q also scaled by (1/8)*log2e
    unsigned short* dst = mat == 0 ? Qh : Kh;
    const float scale = mat == 0 ? 0.18033688011112042f : 1.0f;
#pragma unroll
    for (int ni = 0; ni < 4; ++ni) {
      int n = n0 + wn + ni * 16 + (lane & 15);
      int h = n >> 6, d = n & 63, fi = d >> 1;
      size_t base = (size_t)(b * 16 + h) * 131072 + d;
#pragma unroll
      for (int mi = 0; mi < 4; ++mi) {
#pragma unroll
        for (int r = 0; r < 4; ++r) {
          int s = sbase + mi * 16 + r;
          float v = acc[mi][ni][r];
          float p = __shfl_xor(v, 1);
          float c = cosT[(s << 5) + fi], sn = sinT[(s << 5) + fi];
          float ov = (d & 1) ? (p * sn + v * c) : (v * c - p * sn);
          dst[base + (size_t)s * 64] = f2bf(ov * scale);
        }
      }
    }
  } else {  // V: transposed bf16 store Vt [bh][d][s]
#pragma unroll
    for (int ni = 0; ni < 4; ++ni) {
      int n = n0 + wn + ni * 16 + (lane & 15);
      int h = n >> 6, d = n & 63;
#pragma unroll
      for (int mi = 0; mi < 4; ++mi) {
        u16x4 pk;
        pk.x = f2bf(acc[mi][ni][0]); pk.y = f2bf(acc[mi][ni][1]);
        pk.z = f2bf(acc[mi][ni][2]); pk.w = f2bf(acc[mi][ni][3]);
        int s = sbase + mi * 16;
        *(u16x4*)(Vt + ((size_t)(b * 16 + h) * 64 + d) * 2048 + s) = pk;
      }
    }
  }
}

// ---------------- Wo GEMM: A bf16 [8192][1024], out f32 + bias ----------------
__global__ __launch_bounds__(256) void gemm_wo(const unsigned short* __restrict__ Ab,
                                               const unsigned short* __restrict__ W,
                                               float* __restrict__ outp,
                                               const float* __restrict__ bo) {
  __shared__ __align__(16) unsigned short Asb[128 * 32];
  __shared__ __align__(16) unsigned short Bs[128 * 32];

  const int tid = threadIdx.x;
  const int lane = tid & 63;
  const int wave = tid >> 6;
  const int flat = blockIdx.x;
  const int wgid = (flat & 7) * 64 + (flat >> 3);
  const int m0 = (wgid >> 3) * 128;
  const int n0 = (wgid & 7) * 128;
  const int wm = (wave >> 1) * 64;
  const int wn = (wave & 1) * 64;
  const int hi2 = lane >> 4;

  f32x4 acc[4][4] = {};

  for (int kt = 0; kt < 32; ++kt) {
    const int k0 = kt * 32;
#pragma unroll
    for (int i = 0; i < 2; ++i) {
      int g = i * 256 + tid;
      int row = g >> 2, u = g & 3;
      ld_lds16(Ab + (size_t)(m0 + row) * 1024 + k0 + ((u ^ ((row >> 1) & 3)) << 3),
               Asb + ((i * 256 + wave * 64) << 3));
      ld_lds16(W + (size_t)(n0 + row) * 1024 + k0 + ((u ^ ((row >> 1) & 3)) << 3),
               Bs + ((i * 256 + wave * 64) << 3));
    }
    __syncthreads();

    bf16x8 af[4], bfr[4];
#pragma unroll
    for (int x = 0; x < 4; ++x) {
      int row = wm + x * 16 + (lane & 15);
      af[x] = *(const bf16x8*)(Asb + row * 32 + ((hi2 ^ ((row >> 1) & 3)) << 3));
      int brow = wn + x * 16 + (lane & 15);
      bfr[x] = *(const bf16x8*)(Bs + brow * 32 + ((hi2 ^ ((brow >> 1) & 3)) << 3));
    }
#pragma unroll
    for (int mi = 0; mi < 4; ++mi)
#pragma unroll
      for (int ni = 0; ni < 4; ++ni)
        acc[mi][ni] = __builtin_amdgcn_mfma_f32_16x16x32_bf16(af[mi], bfr[ni], acc[mi][ni], 0, 0, 0);
    __syncthreads();
  }

#pragma unroll
  for (int ni = 0; ni < 4; ++ni) {
    int n = n0 + wn + ni * 16 + (lane & 15);
    float bias = bo[n];
#pragma unroll
    for (int mi = 0; mi < 4; ++mi)
#pragma unroll
      for (int r = 0; r < 4; ++r) {
        int m = m0 + wm + mi * 16 + ((lane >> 4) << 2) + r;
        outp[(size_t)m * 1024 + n] = acc[mi][ni][r] + bias;
      }
  }
}

// exp2 + sum + pack one 64-key S^T pair -> PV A-fragments; returns lane-partial sum
DEVI float tile_sm(f32x16& s0, f32x16& s1, bf16x8* pa) {
  float a0 = 0.f, a1 = 0.f, a2 = 0.f, a3 = 0.f;
#pragma unroll
  for (int r = 0; r < 16; r += 4) {
    s0[r] = __builtin_amdgcn_exp2f(s0[r]);         a0 += s0[r];
    s0[r + 1] = __builtin_amdgcn_exp2f(s0[r + 1]); a1 += s0[r + 1];
    s0[r + 2] = __builtin_amdgcn_exp2f(s0[r + 2]); a2 += s0[r + 2];
    s0[r + 3] = __builtin_amdgcn_exp2f(s0[r + 3]); a3 += s0[r + 3];
  }
#pragma unroll
  for (int r = 0; r < 16; r += 4) {
    s1[r] = __builtin_amdgcn_exp2f(s1[r]);         a0 += s1[r];
    s1[r + 1] = __builtin_amdgcn_exp2f(s1[r + 1]); a1 += s1[r + 1];
    s1[r + 2] = __builtin_amdgcn_exp2f(s1[r + 2]); a2 += s1[r + 2];
    s1[r + 3] = __builtin_amdgcn_exp2f(s1[r + 3]); a3 += s1[r + 3];
  }
#pragma unroll
  for (int blk = 0; blk < 2; ++blk) {
    const f32x16& s = blk ? s1 : s0;
#pragma unroll
    for (int half = 0; half < 2; ++half) {
      int o = half * 8;
      unsigned u0 = cvtpk(s[o + 0], s[o + 1]);
      unsigned u1 = cvtpk(s[o + 2], s[o + 3]);
      unsigned u2 = cvtpk(s[o + 4], s[o + 5]);
      unsigned u3 = cvtpk(s[o + 6], s[o + 7]);
      auto r02 = __builtin_amdgcn_permlane32_swap(u0, u2, false, false);
      auto r13 = __builtin_amdgcn_permlane32_swap(u1, u3, false, false);
      union { u32x4 u; bf16x8 v; } f;
      f.u.x = r02[0]; f.u.y = r13[0]; f.u.z = r02[1]; f.u.w = r13[1];
      pa[blk * 2 + half] = f.v;
    }
  }
  return (a0 + a1) + (a2 + a3);
}

// ---------------- flash attention: KVBLK=64, 64 q/wave, race-free two-barrier rounds ----------------
// Round: stage(kt+1) -> vmcnt(4) [tile kt landed; kt+1 in flight] -> barrier1 ->
// hoisted K+V frag reads -> QK -> SM -> PV -> barrier2 (WAR fix: reads of cur done
// before next round's DMA overwrites it).
__global__ __launch_bounds__(256, 2) void attn_kernel(const unsigned short* __restrict__ Qh,
                                                      const unsigned short* __restrict__ Kh,
                                                      const unsigned short* __restrict__ Vt,
                                                      unsigned short* __restrict__ AOb) {
  __shared__ __align__(16) unsigned short SM[4][4096];  // K0,V0,K1,V1

  const int tid = threadIdx.x, lane = tid & 63, wave = tid >> 6;
  const int lid = blockIdx.x;  // 0..511
  const int xcd = lid & 7, slot = lid >> 3;
  const int bh = xcd * 8 + (slot >> 3);  // 8 bh per XCD
  const int qb = slot & 7;
  const int q0 = qb * 256 + wave * 64;
  const int lq = lane & 31, hi = lane >> 5;

  const unsigned short* Qgb = Qh + (size_t)bh * 131072;
  const unsigned short* Kgb = Kh + (size_t)bh * 131072;
  const unsigned short* Vgb = Vt + (size_t)bh * 131072;

  bf16x8 qfa[4], qfb[4];
#pragma unroll
  for (int st = 0; st < 4; ++st) {
    qfa[st] = *(const bf16x8*)(Qgb + (size_t)(q0 + lq) * 64 + st * 16 + hi * 8);
    qfb[st] = *(const bf16x8*)(Qgb + (size_t)(q0 + 32 + lq) * 64 + st * 16 + hi * 8);
  }

  const int r0 = wave * 8 + (lane >> 3);
  const int u0 = lane & 7;
  const int sw = (u0 ^ (r0 & 7)) << 3;
  const unsigned short* kp0 = Kgb + r0 * 64 + sw;
  const unsigned short* kp1 = Kgb + (32 + r0) * 64 + sw;
  const unsigned short* vp0 = Vgb + (size_t)r0 * 2048 + sw;
  const unsigned short* vp1 = Vgb + (size_t)(32 + r0) * 2048 + sw;
  const int d0 = wave * 512, d1 = 2048 + wave * 512;

  auto stage = [&](int buf, int kt) {
    unsigned short* Kd = SM[buf * 2];
    unsigned short* Vd = SM[buf * 2 + 1];
    ld_lds16(kp0 + kt * 4096, Kd + d0);
    ld_lds16(kp1 + kt * 4096, Kd + d1);
    ld_lds16(vp0 + kt * 64, Vd + d0);
    ld_lds16(vp1 + kt * 64, Vd + d1);
  };
  auto frag = [&](const unsigned short* base, int row, int c) -> bf16x8 {
    return *(const bf16x8*)(base + row * 64 + (((c ^ (row & 7)) << 3)));
  };

  f32x16 o0a = {}, o1a = {}, o0b = {}, o1b = {};
  float lsA = 0.f, lsB = 0.f;

  stage(0, 0);

  for (int kt = 0; kt < 32; ++kt) {
    const int cur = kt & 1;
    if (kt < 31) {
      stage(cur ^ 1, kt + 1);
      asm volatile("s_waitcnt vmcnt(4)" ::: "memory");  // tile kt landed; kt+1 in flight
    } else {
      asm volatile("s_waitcnt vmcnt(0)" ::: "memory");
    }
    __builtin_amdgcn_s_barrier();  // barrier1: all waves' tile-kt DMA visible
    const unsigned short* Kc = SM[cur * 2];
    const unsigned short* Vc = SM[cur * 2 + 1];

    // all frag reads up front: V-read latency hides under QK+SM
    bf16x8 kf0[4], kf1[4], vf0[4], vf1[4];
#pragma unroll
    for (int st = 0; st < 4; ++st) {
      kf0[st] = frag(Kc, lq, st * 2 + hi);
      kf1[st] = frag(Kc, 32 + lq, st * 2 + hi);
      vf0[st] = frag(Vc, lq, st * 2 + hi);
      vf1[st] = frag(Vc, 32 + lq, st * 2 + hi);
    }

    f32x16 s0a = {}, s1a = {}, s0b = {}, s1b = {};
#pragma unroll
    for (int st = 0; st < 4; ++st) {
      s0a = __builtin_amdgcn_mfma_f32_32x32x16_bf16(kf0[st], qfa[st], s0a, 0, 0, 0);
      s1a = __builtin_amdgcn_mfma_f32_32x32x16_bf16(kf1[st], qfa[st], s1a, 0, 0, 0);
      s0b = __builtin_amdgcn_mfma_f32_32x32x16_bf16(kf0[st], qfb[st], s0b, 0, 0, 0);
      s1b = __builtin_amdgcn_mfma_f32_32x32x16_bf16(kf1[st], qfb[st], s1b, 0, 0, 0);
    }

    bf16x8 paA[4], paB[4];
    lsA += tile_sm(s0a, s1a, paA);
    lsB += tile_sm(s0b, s1b, paB);

#pragma unroll
    for (int kc = 0; kc < 4; ++kc) {
      o0a = __builtin_amdgcn_mfma_f32_32x32x16_bf16(paA[kc], vf0[kc], o0a, 0, 0, 0);
      o1a = __builtin_amdgcn_mfma_f32_32x32x16_bf16(paA[kc], vf1[kc], o1a, 0, 0, 0);
      o0b = __builtin_amdgcn_mfma_f32_32x32x16_bf16(paB[kc], vf0[kc], o0b, 0, 0, 0);
      o1b = __builtin_amdgcn_mfma_f32_32x32x16_bf16(paB[kc], vf1[kc], o1b, 0, 0, 0);
    }

    if (kt < 31) {
      __builtin_amdgcn_s_barrier();  // barrier2: reads of cur done before next round's
    }                                // stage overwrites it (WAR fix)
  }

  lsA += __shfl_xor(lsA, 32);
  lsB += __shfl_xor(lsB, 32);
  const int b = bh >> 4, h = bh & 15;
#pragma unroll
  for (int r = 0; r < 16; ++r) {
    int row = (r & 3) + 8 * (r >> 2) + 4 * hi;
    float ia = 1.0f / __shfl(lsA, row);
    float ib = 1.0f / __shfl(lsB, row);
    unsigned short* da = AOb + (size_t)(b * 2048 + q0 + row) * 1024 + h * 64;
    unsigned short* db = AOb + (size_t)(b * 2048 + q0 + 32 + row) * 1024 + h * 64;
    da[lq] = f2bf(o0a[r] * ia);
    da[32 + lq] = f2bf(o1a[r] * ia);
    db[lq] = f2bf(o0b[r] * ib);
    db[32 + lq] = f2bf(o1b[r] * ib);
  }
}

extern "C" void kernel_launch(void* const* d_in, const int* in_sizes, int n_in,
                              void* d_out, int out_size, void* d_ws, size_t ws_size,
                              hipStream_t stream) {
  const float* query = (const float*)d_in[0];
  const float* key = (const float*)d_in[1];
  const float* value = (const float*)d_in[2];
  const float* Wq = (const float*)d_in[3];
  const float* Wk = (const float*)d_in[4];
  const float* Wv = (const float*)d_in[5];
  const float* Wo = (const float*)d_in[6];
  const float* bo = (const float*)d_in[7];

  char* ws = (char*)d_ws;
  unsigned short* Wb = (unsigned short*)(ws + WS_WB);
  float* cosT = (float*)(ws + WS_COS);
  float* sinT = (float*)(ws + WS_SIN);
  unsigned short* Qh = (unsigned short*)(ws + WS_QH);
  unsigned short* Kh = (unsigned short*)(ws + WS_KH);
  unsigned short* Vt = (unsigned short*)(ws + WS_VT);
  unsigned short* AOb = (unsigned short*)(ws + WS_AO);

  prep<<<dim3(1024, 5), 256, 0, stream>>>(Wq, Wk, Wv, Wo, Wb, cosT, sinT);
  gemm_qkv<<<dim3(512, 3), 256, 0, stream>>>(query, key, value, Wb, Qh, Kh, Vt, cosT, sinT);
  attn_kernel<<<512, 256, 0, stream>>>(Qh, Kh, Vt, AOb);
  gemm_wo<<<512, 256, 0, stream>>>(AOb, Wb + 3145728, (float*)d_out, bo);
}

// Round 17
// 205.386 us; speedup vs baseline: 1.2031x; 1.0536x over previous
//
#include <hip/hip_runtime.h>
#include <math.h>

typedef __attribute__((ext_vector_type(4))) float f32x4;
typedef __attribute__((ext_vector_type(16))) float f32x16;
typedef __attribute__((ext_vector_type(8))) __bf16 bf16x8;
typedef __attribute__((ext_vector_type(4))) unsigned int u32x4;
typedef __attribute__((ext_vector_type(4))) unsigned short u16x4;

#define DEVI __device__ __forceinline__

// B=4, S=2048, E=1024, H=16, D=64, M=B*S=8192
constexpr size_t WS_WB  = 0;
constexpr size_t WS_COS = 4ull * 1024 * 1024 * 2;
constexpr size_t WS_SIN = WS_COS + 2048 * 32 * 4;
constexpr size_t WS_QH  = WS_SIN + 2048 * 32 * 4;
constexpr size_t WS_KH  = WS_QH + 64ull * 2048 * 64 * 2;
constexpr size_t WS_VT  = WS_KH + 64ull * 2048 * 64 * 2;
constexpr size_t WS_AO  = WS_VT + 64ull * 64 * 2048 * 2;  // AO bf16 [8192][1024]

DEVI unsigned short f2bf(float x) {
  union { float f; unsigned int u; } v; v.f = x;
  unsigned int r = v.u + 0x7fffu + ((v.u >> 16) & 1u);  // RNE
  return (unsigned short)(r >> 16);
}

DEVI unsigned cvtpk(float a, float b) {
  union { __bf16 h[2]; unsigned u; } x;
  x.h[0] = (__bf16)a; x.h[1] = (__bf16)b;
  return x.u;
}

// async global->LDS DMA, 16B/lane; dest = wave-uniform base, HW adds lane*16
DEVI void ld_lds16(const void* g, void* l) {
  __builtin_amdgcn_global_load_lds((const __attribute__((address_space(1))) void*)g,
                                   (__attribute__((address_space(3))) void*)l, 16, 0, 0);
}

// ---------------- prep: weights fp32->bf16 (y<4) + RoPE tables (y==4) ----------------
__global__ __launch_bounds__(256) void prep(const float* __restrict__ w0,
                                            const float* __restrict__ w1,
                                            const float* __restrict__ w2,
                                            const float* __restrict__ w3,
                                            unsigned short* __restrict__ out,
                                            float* __restrict__ cosT,
                                            float* __restrict__ sinT) {
  if (blockIdx.y == 4) {
    if (blockIdx.x >= 256) return;
    int idx = blockIdx.x * 256 + threadIdx.x;  // 65536 = 2048*32
    int s = idx >> 5, i = idx & 31;
    double ang = (double)s * pow(10000.0, -(double)i / 32.0);
    cosT[idx] = (float)cos(ang);
    sinT[idx] = (float)sin(ang);
    return;
  }
  const float* w = blockIdx.y == 0 ? w0 : blockIdx.y == 1 ? w1 : blockIdx.y == 2 ? w2 : w3;
  int i = (blockIdx.x * 256 + threadIdx.x) * 4;
  f32x4 v = *(const f32x4*)(w + i);
  u16x4 o;
  o.x = f2bf(v.x); o.y = f2bf(v.y); o.z = f2bf(v.z); o.w = f2bf(v.w);
  *(u16x4*)(out + (size_t)blockIdx.y * 1048576 + i) = o;
}

// ---------------- merged QKV GEMM, STATIC double-buffer: grid (512, 3) ----------------
// Combines the two independently-verified wins: (a) merged dispatch (R15 A/B: tail
// overlap across blockIdx.y, 84 vs 115 us), (b) R8/R9 static-dbuf loop (distinct LDS
// arrays -> compiler-visible aliasing, no forced DMA drain before ds_reads; 1 barrier
// per K-step). Race-free: reads(cur) follow prev iter's vmcnt(0)+barrier (cur drained);
// stage(other) follows the barrier that fenced other's readers one iter earlier.
__global__ __launch_bounds__(256) void gemm_qkv(const float* __restrict__ Aq,
                                                const float* __restrict__ Ak,
                                                const float* __restrict__ Av,
                                                const unsigned short* __restrict__ Wb,
                                                unsigned short* __restrict__ Qh,
                                                unsigned short* __restrict__ Kh,
                                                unsigned short* __restrict__ Vt,
                                                const float* __restrict__ cosT,
                                                const float* __restrict__ sinT) {
  __shared__ __align__(16) float As0[128 * 32];            // [128][32] f32
  __shared__ __align__(16) float As1[128 * 32];
  __shared__ __align__(16) unsigned short Bs0[128 * 32];   // [128][32] bf16
  __shared__ __align__(16) unsigned short Bs1[128 * 32];

  const int mat = blockIdx.y;  // 0=Q 1=K 2=V
  const float* A = mat == 0 ? Aq : mat == 1 ? Ak : Av;
  const unsigned short* W = Wb + (size_t)mat * 1048576;

  const int tid = threadIdx.x;
  const int lane = tid & 63;
  const int wave = tid >> 6;
  const int flat = blockIdx.x;
  const int wgid = (flat & 7) * 64 + (flat >> 3);  // XCD chunk-swizzle
  const int m0 = (wgid >> 3) * 128;
  const int n0 = (wgid & 7) * 128;
  const int wm = (wave >> 1) * 64;
  const int wn = (wave & 1) * 64;
  const int hi2 = lane >> 4;

  f32x4 acc[4][4] = {};

  auto stage = [&](float* AsD, unsigned short* BsD, int kt) {
    const int k0 = kt * 32;
#pragma unroll
    for (int i = 0; i < 4; ++i) {  // A f32 rows 128B: swz u^(row&7) on 16B units
      int g = i * 256 + tid;
      int row = g >> 3, u = g & 7;
      ld_lds16(A + (size_t)(m0 + row) * 1024 + k0 + ((u ^ (row & 7)) << 2),
               AsD + ((i * 256 + wave * 64) << 2));
    }
#pragma unroll
    for (int i = 0; i < 2; ++i) {  // W bf16 rows 64B: swz u^((row>>1)&3)
      int g = i * 256 + tid;
      int row = g >> 2, u = g & 3;
      ld_lds16(W + (size_t)(n0 + row) * 1024 + k0 + ((u ^ ((row >> 1) & 3)) << 3),
               BsD + ((i * 256 + wave * 64) << 3));
    }
  };

  auto round = [&](const float* AsC, const unsigned short* BsC, int nkt,
                   float* AsN, unsigned short* BsN) {
    // ---- frag reads from CURRENT static buffers (drained by prev iter's fence) ----
    bf16x8 af[4], bfr[4];
#pragma unroll
    for (int x = 0; x < 4; ++x) {
      int row = wm + x * 16 + (lane & 15);
      int swz = row & 7;
      f32x4 a0 = *(const f32x4*)(AsC + row * 32 + (((hi2 * 2) ^ swz) << 2));
      f32x4 a1 = *(const f32x4*)(AsC + row * 32 + (((hi2 * 2 + 1) ^ swz) << 2));
      union { u32x4 u; bf16x8 v; } f;
      f.u.x = cvtpk(a0.x, a0.y); f.u.y = cvtpk(a0.z, a0.w);
      f.u.z = cvtpk(a1.x, a1.y); f.u.w = cvtpk(a1.z, a1.w);
      af[x] = f.v;
      int brow = wn + x * 16 + (lane & 15);
      bfr[x] = *(const bf16x8*)(BsC + brow * 32 + ((hi2 ^ ((brow >> 1) & 3)) << 3));
    }
    // ---- prefetch next K-tile into the OTHER static buffers: flies under MFMA ----
    if (nkt < 32) stage(AsN, BsN, nkt);
    // ---- MFMA ----
#pragma unroll
    for (int mi = 0; mi < 4; ++mi)
#pragma unroll
      for (int ni = 0; ni < 4; ++ni)
        acc[mi][ni] = __builtin_amdgcn_mfma_f32_16x16x32_bf16(af[mi], bfr[ni], acc[mi][ni], 0, 0, 0);
    // ---- own stage landed (had full MFMA phase) -> block-wide fence ----
    asm volatile("s_waitcnt vmcnt(0)" ::: "memory");
    __builtin_amdgcn_s_barrier();
  };

  stage(As0, Bs0, 0);
  asm volatile("s_waitcnt vmcnt(0)" ::: "memory");
  __builtin_amdgcn_s_barrier();

  for (int kt = 0; kt < 32; kt += 2) {
    round(As0, Bs0, kt + 1, As1, Bs1);
    round(As1, Bs1, kt + 2, As0, Bs0);
  }

  const int b = m0 >> 11;
  const int sbase = (m0 & 2047) + wm + ((lane >> 4) << 2);

  if (mat < 2) {  // Q/K: RoPE + bf16 store [bh][s][d]; Q also scaled by (1/8)*log2e
    unsigned short* dst = mat == 0 ? Qh : Kh;
    const float scale = mat == 0 ? 0.18033688011112042f : 1.0f;
#pragma unroll
    for (int ni = 0; ni < 4; ++ni) {
      int n = n0 + wn + ni * 16 + (lane & 15);
      int h = n >> 6, d = n & 63, fi = d >> 1;
      size_t base = (size_t)(b * 16 + h) * 131072 + d;
#pragma unroll
      for (int mi = 0; mi < 4; ++mi) {
#pragma unroll
        for (int r = 0; r < 4; ++r) {
          int s = sbase + mi * 16 + r;
          float v = acc[mi][ni][r];
          float p = __shfl_xor(v, 1);
          float c = cosT[(s << 5) + fi], sn = sinT[(s << 5) + fi];
          float ov = (d & 1) ? (p * sn + v * c) : (v * c - p * sn);
          dst[base + (size_t)s * 64] = f2bf(ov * scale);
        }
      }
    }
  } else {  // V: transposed bf16 store Vt [bh][d][s]
#pragma unroll
    for (int ni = 0; ni < 4; ++ni) {
      int n = n0 + wn + ni * 16 + (lane & 15);
      int h = n >> 6, d = n & 63;
#pragma unroll
      for (int mi = 0; mi < 4; ++mi) {
        u16x4 pk;
        pk.x = f2bf(acc[mi][ni][0]); pk.y = f2bf(acc[mi][ni][1]);
        pk.z = f2bf(acc[mi][ni][2]); pk.w = f2bf(acc[mi][ni][3]);
        int s = sbase + mi * 16;
        *(u16x4*)(Vt + ((size_t)(b * 16 + h) * 64 + d) * 2048 + s) = pk;
      }
    }
  }
}

// ---------------- Wo GEMM: A bf16 [8192][1024], out f32 + bias (R16-exact) ----------------
__global__ __launch_bounds__(256) void gemm_wo(const unsigned short* __restrict__ Ab,
                                               const unsigned short* __restrict__ W,
                                               float* __restrict__ outp,
                                               const float* __restrict__ bo) {
  __shared__ __align__(16) unsigned short Asb[128 * 32];
  __shared__ __align__(16) unsigned short Bs[128 * 32];

  const int tid = threadIdx.x;
  const int lane = tid & 63;
  const int wave = tid >> 6;
  const int flat = blockIdx.x;
  const int wgid = (flat & 7) * 64 + (flat >> 3);
  const int m0 = (wgid >> 3) * 128;
  const int n0 = (wgid & 7) * 128;
  const int wm = (wave >> 1) * 64;
  const int wn = (wave & 1) * 64;
  const int hi2 = lane >> 4;

  f32x4 acc[4][4] = {};

  for (int kt = 0; kt < 32; ++kt) {
    const int k0 = kt * 32;
#pragma unroll
    for (int i = 0; i < 2; ++i) {
      int g = i * 256 + tid;
      int row = g >> 2, u = g & 3;
      ld_lds16(Ab + (size_t)(m0 + row) * 1024 + k0 + ((u ^ ((row >> 1) & 3)) << 3),
               Asb + ((i * 256 + wave * 64) << 3));
      ld_lds16(W + (size_t)(n0 + row) * 1024 + k0 + ((u ^ ((row >> 1) & 3)) << 3),
               Bs + ((i * 256 + wave * 64) << 3));
    }
    __syncthreads();

    bf16x8 af[4], bfr[4];
#pragma unroll
    for (int x = 0; x < 4; ++x) {
      int row = wm + x * 16 + (lane & 15);
      af[x] = *(const bf16x8*)(Asb + row * 32 + ((hi2 ^ ((row >> 1) & 3)) << 3));
      int brow = wn + x * 16 + (lane & 15);
      bfr[x] = *(const bf16x8*)(Bs + brow * 32 + ((hi2 ^ ((brow >> 1) & 3)) << 3));
    }
#pragma unroll
    for (int mi = 0; mi < 4; ++mi)
#pragma unroll
      for (int ni = 0; ni < 4; ++ni)
        acc[mi][ni] = __builtin_amdgcn_mfma_f32_16x16x32_bf16(af[mi], bfr[ni], acc[mi][ni], 0, 0, 0);
    __syncthreads();
  }

#pragma unroll
  for (int ni = 0; ni < 4; ++ni) {
    int n = n0 + wn + ni * 16 + (lane & 15);
    float bias = bo[n];
#pragma unroll
    for (int mi = 0; mi < 4; ++mi)
#pragma unroll
      for (int r = 0; r < 4; ++r) {
        int m = m0 + wm + mi * 16 + ((lane >> 4) << 2) + r;
        outp[(size_t)m * 1024 + n] = acc[mi][ni][r] + bias;
      }
  }
}

// exp2 + sum + pack one 64-key S^T pair -> PV A-fragments; returns lane-partial sum
DEVI float tile_sm(f32x16& s0, f32x16& s1, bf16x8* pa) {
  float a0 = 0.f, a1 = 0.f, a2 = 0.f, a3 = 0.f;
#pragma unroll
  for (int r = 0; r < 16; r += 4) {
    s0[r] = __builtin_amdgcn_exp2f(s0[r]);         a0 += s0[r];
    s0[r + 1] = __builtin_amdgcn_exp2f(s0[r + 1]); a1 += s0[r + 1];
    s0[r + 2] = __builtin_amdgcn_exp2f(s0[r + 2]); a2 += s0[r + 2];
    s0[r + 3] = __builtin_amdgcn_exp2f(s0[r + 3]); a3 += s0[r + 3];
  }
#pragma unroll
  for (int r = 0; r < 16; r += 4) {
    s1[r] = __builtin_amdgcn_exp2f(s1[r]);         a0 += s1[r];
    s1[r + 1] = __builtin_amdgcn_exp2f(s1[r + 1]); a1 += s1[r + 1];
    s1[r + 2] = __builtin_amdgcn_exp2f(s1[r + 2]); a2 += s1[r + 2];
    s1[r + 3] = __builtin_amdgcn_exp2f(s1[r + 3]); a3 += s1[r + 3];
  }
#pragma unroll
  for (int blk = 0; blk < 2; ++blk) {
    const f32x16& s = blk ? s1 : s0;
#pragma unroll
    for (int half = 0; half < 2; ++half) {
      int o = half * 8;
      unsigned u0 = cvtpk(s[o + 0], s[o + 1]);
      unsigned u1 = cvtpk(s[o + 2], s[o + 3]);
      unsigned u2 = cvtpk(s[o + 4], s[o + 5]);
      unsigned u3 = cvtpk(s[o + 6], s[o + 7]);
      auto r02 = __builtin_amdgcn_permlane32_swap(u0, u2, false, false);
      auto r13 = __builtin_amdgcn_permlane32_swap(u1, u3, false, false);
      union { u32x4 u; bf16x8 v; } f;
      f.u.x = r02[0]; f.u.y = r13[0]; f.u.z = r02[1]; f.u.w = r13[1];
      pa[blk * 2 + half] = f.v;
    }
  }
  return (a0 + a1) + (a2 + a3);
}

// ---------------- flash attention: KVBLK=64, 64 q/wave, race-free two-barrier rounds (R16) ----------------
__global__ __launch_bounds__(256, 2) void attn_kernel(const unsigned short* __restrict__ Qh,
                                                      const unsigned short* __restrict__ Kh,
                                                      const unsigned short* __restrict__ Vt,
                                                      unsigned short* __restrict__ AOb) {
  __shared__ __align__(16) unsigned short SM[4][4096];  // K0,V0,K1,V1

  const int tid = threadIdx.x, lane = tid & 63, wave = tid >> 6;
  const int lid = blockIdx.x;  // 0..511
  const int xcd = lid & 7, slot = lid >> 3;
  const int bh = xcd * 8 + (slot >> 3);  // 8 bh per XCD
  const int qb = slot & 7;
  const int q0 = qb * 256 + wave * 64;
  const int lq = lane & 31, hi = lane >> 5;

  const unsigned short* Qgb = Qh + (size_t)bh * 131072;
  const unsigned short* Kgb = Kh + (size_t)bh * 131072;
  const unsigned short* Vgb = Vt + (size_t)bh * 131072;

  bf16x8 qfa[4], qfb[4];
#pragma unroll
  for (int st = 0; st < 4; ++st) {
    qfa[st] = *(const bf16x8*)(Qgb + (size_t)(q0 + lq) * 64 + st * 16 + hi * 8);
    qfb[st] = *(const bf16x8*)(Qgb + (size_t)(q0 + 32 + lq) * 64 + st * 16 + hi * 8);
  }

  const int r0 = wave * 8 + (lane >> 3);
  const int u0 = lane & 7;
  const int sw = (u0 ^ (r0 & 7)) << 3;
  const unsigned short* kp0 = Kgb + r0 * 64 + sw;
  const unsigned short* kp1 = Kgb + (32 + r0) * 64 + sw;
  const unsigned short* vp0 = Vgb + (size_t)r0 * 2048 + sw;
  const unsigned short* vp1 = Vgb + (size_t)(32 + r0) * 2048 + sw;
  const int d0 = wave * 512, d1 = 2048 + wave * 512;

  auto stage = [&](int buf, int kt) {
    unsigned short* Kd = SM[buf * 2];
    unsigned short* Vd = SM[buf * 2 + 1];
    ld_lds16(kp0 + kt * 4096, Kd + d0);
    ld_lds16(kp1 + kt * 4096, Kd + d1);
    ld_lds16(vp0 + kt * 64, Vd + d0);
    ld_lds16(vp1 + kt * 64, Vd + d1);
  };
  auto frag = [&](const unsigned short* base, int row, int c) -> bf16x8 {
    return *(const bf16x8*)(base + row * 64 + (((c ^ (row & 7)) << 3)));
  };

  f32x16 o0a = {}, o1a = {}, o0b = {}, o1b = {};
  float lsA = 0.f, lsB = 0.f;

  stage(0, 0);

  for (int kt = 0; kt < 32; ++kt) {
    const int cur = kt & 1;
    if (kt < 31) {
      stage(cur ^ 1, kt + 1);
      asm volatile("s_waitcnt vmcnt(4)" ::: "memory");  // tile kt landed; kt+1 in flight
    } else {
      asm volatile("s_waitcnt vmcnt(0)" ::: "memory");
    }
    __builtin_amdgcn_s_barrier();  // barrier1: all waves' tile-kt DMA visible
    const unsigned short* Kc = SM[cur * 2];
    const unsigned short* Vc = SM[cur * 2 + 1];

    // all frag reads up front: V-read latency hides under QK+SM
    bf16x8 kf0[4], kf1[4], vf0[4], vf1[4];
#pragma unroll
    for (int st = 0; st < 4; ++st) {
      kf0[st] = frag(Kc, lq, st * 2 + hi);
      kf1[st] = frag(Kc, 32 + lq, st * 2 + hi);
      vf0[st] = frag(Vc, lq, st * 2 + hi);
      vf1[st] = frag(Vc, 32 + lq, st * 2 + hi);
    }

    f32x16 s0a = {}, s1a = {}, s0b = {}, s1b = {};
#pragma unroll
    for (int st = 0; st < 4; ++st) {
      s0a = __builtin_amdgcn_mfma_f32_32x32x16_bf16(kf0[st], qfa[st], s0a, 0, 0, 0);
      s1a = __builtin_amdgcn_mfma_f32_32x32x16_bf16(kf1[st], qfa[st], s1a, 0, 0, 0);
      s0b = __builtin_amdgcn_mfma_f32_32x32x16_bf16(kf0[st], qfb[st], s0b, 0, 0, 0);
      s1b = __builtin_amdgcn_mfma_f32_32x32x16_bf16(kf1[st], qfb[st], s1b, 0, 0, 0);
    }

    bf16x8 paA[4], paB[4];
    lsA += tile_sm(s0a, s1a, paA);
    lsB += tile_sm(s0b, s1b, paB);

#pragma unroll
    for (int kc = 0; kc < 4; ++kc) {
      o0a = __builtin_amdgcn_mfma_f32_32x32x16_bf16(paA[kc], vf0[kc], o0a, 0, 0, 0);
      o1a = __builtin_amdgcn_mfma_f32_32x32x16_bf16(paA[kc], vf1[kc], o1a, 0, 0, 0);
      o0b = __builtin_amdgcn_mfma_f32_32x32x16_bf16(paB[kc], vf0[kc], o0b, 0, 0, 0);
      o1b = __builtin_amdgcn_mfma_f32_32x32x16_bf16(paB[kc], vf1[kc], o1b, 0, 0, 0);
    }

    if (kt < 31) {
      __builtin_amdgcn_s_barrier();  // barrier2: reads of cur done before next round's
    }                                // stage overwrites it (WAR fix)
  }

  lsA += __shfl_xor(lsA, 32);
  lsB += __shfl_xor(lsB, 32);
  const int b = bh >> 4, h = bh & 15;
#pragma unroll
  for (int r = 0; r < 16; ++r) {
    int row = (r & 3) + 8 * (r >> 2) + 4 * hi;
    float ia = 1.0f / __shfl(lsA, row);
    float ib = 1.0f / __shfl(lsB, row);
    unsigned short* da = AOb + (size_t)(b * 2048 + q0 + row) * 1024 + h * 64;
    unsigned short* db = AOb + (size_t)(b * 2048 + q0 + 32 + row) * 1024 + h * 64;
    da[lq] = f2bf(o0a[r] * ia);
    da[32 + lq] = f2bf(o1a[r] * ia);
    db[lq] = f2bf(o0b[r] * ib);
    db[32 + lq] = f2bf(o1b[r] * ib);
  }
}

extern "C" void kernel_launch(void* const* d_in, const int* in_sizes, int n_in,
                              void* d_out, int out_size, void* d_ws, size_t ws_size,
                              hipStream_t stream) {
  const float* query = (const float*)d_in[0];
  const float* key = (const float*)d_in[1];
  const float* value = (const float*)d_in[2];
  const float* Wq = (const float*)d_in[3];
  const float* Wk = (const float*)d_in[4];
  const float* Wv = (const float*)d_in[5];
  const float* Wo = (const float*)d_in[6];
  const float* bo = (const float*)d_in[7];

  char* ws = (char*)d_ws;
  unsigned short* Wb = (unsigned short*)(ws + WS_WB);
  float* cosT = (float*)(ws + WS_COS);
  float* sinT = (float*)(ws + WS_SIN);
  unsigned short* Qh = (unsigned short*)(ws + WS_QH);
  unsigned short* Kh = (unsigned short*)(ws + WS_KH);
  unsigned short* Vt = (unsigned short*)(ws + WS_VT);
  unsigned short* AOb = (unsigned short*)(ws + WS_AO);

  prep<<<dim3(1024, 5), 256, 0, stream>>>(Wq, Wk, Wv, Wo, Wb, cosT, sinT);
  gemm_qkv<<<dim3(512, 3), 256, 0, stream>>>(query, key, value, Wb, Qh, Kh, Vt, cosT, sinT);
  attn_kernel<<<512, 256, 0, stream>>>(Qh, Kh, Vt, AOb);
  gemm_wo<<<512, 256, 0, stream>>>(AOb, Wb + 3145728, (float*)d_out, bo);
}

// Round 18
// 204.555 us; speedup vs baseline: 1.2080x; 1.0041x over previous
//
#include <hip/hip_runtime.h>
#include <math.h>

typedef __attribute__((ext_vector_type(4))) float f32x4;
typedef __attribute__((ext_vector_type(16))) float f32x16;
typedef __attribute__((ext_vector_type(8))) __bf16 bf16x8;
typedef __attribute__((ext_vector_type(4))) unsigned int u32x4;
typedef __attribute__((ext_vector_type(4))) unsigned short u16x4;

#define DEVI __device__ __forceinline__

// B=4, S=2048, E=1024, H=16, D=64, M=B*S=8192
constexpr size_t WS_WB  = 0;
constexpr size_t WS_COS = 4ull * 1024 * 1024 * 2;
constexpr size_t WS_SIN = WS_COS + 2048 * 32 * 4;
constexpr size_t WS_QH  = WS_SIN + 2048 * 32 * 4;
constexpr size_t WS_KH  = WS_QH + 64ull * 2048 * 64 * 2;
constexpr size_t WS_VT  = WS_KH + 64ull * 2048 * 64 * 2;
constexpr size_t WS_AO  = WS_VT + 64ull * 64 * 2048 * 2;  // AO bf16 [8192][1024]

DEVI unsigned short f2bf(float x) {
  union { float f; unsigned int u; } v; v.f = x;
  unsigned int r = v.u + 0x7fffu + ((v.u >> 16) & 1u);  // RNE
  return (unsigned short)(r >> 16);
}

DEVI unsigned cvtpk(float a, float b) {
  union { __bf16 h[2]; unsigned u; } x;
  x.h[0] = (__bf16)a; x.h[1] = (__bf16)b;
  return x.u;
}

// async global->LDS DMA, 16B/lane; dest = wave-uniform base, HW adds lane*16
DEVI void ld_lds16(const void* g, void* l) {
  __builtin_amdgcn_global_load_lds((const __attribute__((address_space(1))) void*)g,
                                   (__attribute__((address_space(3))) void*)l, 16, 0, 0);
}

// ---------------- prep: weights fp32->bf16 (y<4) + RoPE tables (y==4) ----------------
__global__ __launch_bounds__(256) void prep(const float* __restrict__ w0,
                                            const float* __restrict__ w1,
                                            const float* __restrict__ w2,
                                            const float* __restrict__ w3,
                                            unsigned short* __restrict__ out,
                                            float* __restrict__ cosT,
                                            float* __restrict__ sinT) {
  if (blockIdx.y == 4) {
    if (blockIdx.x >= 256) return;
    int idx = blockIdx.x * 256 + threadIdx.x;  // 65536 = 2048*32
    int s = idx >> 5, i = idx & 31;
    double ang = (double)s * pow(10000.0, -(double)i / 32.0);
    cosT[idx] = (float)cos(ang);
    sinT[idx] = (float)sin(ang);
    return;
  }
  const float* w = blockIdx.y == 0 ? w0 : blockIdx.y == 1 ? w1 : blockIdx.y == 2 ? w2 : w3;
  int i = (blockIdx.x * 256 + threadIdx.x) * 4;
  f32x4 v = *(const f32x4*)(w + i);
  u16x4 o;
  o.x = f2bf(v.x); o.y = f2bf(v.y); o.z = f2bf(v.z); o.w = f2bf(v.w);
  *(u16x4*)(out + (size_t)blockIdx.y * 1048576 + i) = o;
}

// ---------------- merged QKV GEMM, STATIC double-buffer: grid (512, 3) (R17-proven) ----------------
__global__ __launch_bounds__(256) void gemm_qkv(const float* __restrict__ Aq,
                                                const float* __restrict__ Ak,
                                                const float* __restrict__ Av,
                                                const unsigned short* __restrict__ Wb,
                                                unsigned short* __restrict__ Qh,
                                                unsigned short* __restrict__ Kh,
                                                unsigned short* __restrict__ Vt,
                                                const float* __restrict__ cosT,
                                                const float* __restrict__ sinT) {
  __shared__ __align__(16) float As0[128 * 32];            // [128][32] f32
  __shared__ __align__(16) float As1[128 * 32];
  __shared__ __align__(16) unsigned short Bs0[128 * 32];   // [128][32] bf16
  __shared__ __align__(16) unsigned short Bs1[128 * 32];

  const int mat = blockIdx.y;  // 0=Q 1=K 2=V
  const float* A = mat == 0 ? Aq : mat == 1 ? Ak : Av;
  const unsigned short* W = Wb + (size_t)mat * 1048576;

  const int tid = threadIdx.x;
  const int lane = tid & 63;
  const int wave = tid >> 6;
  const int flat = blockIdx.x;
  const int wgid = (flat & 7) * 64 + (flat >> 3);  // XCD chunk-swizzle
  const int m0 = (wgid >> 3) * 128;
  const int n0 = (wgid & 7) * 128;
  const int wm = (wave >> 1) * 64;
  const int wn = (wave & 1) * 64;
  const int hi2 = lane >> 4;

  f32x4 acc[4][4] = {};

  auto stage = [&](float* AsD, unsigned short* BsD, int kt) {
    const int k0 = kt * 32;
#pragma unroll
    for (int i = 0; i < 4; ++i) {  // A f32 rows 128B: swz u^(row&7) on 16B units
      int g = i * 256 + tid;
      int row = g >> 3, u = g & 7;
      ld_lds16(A + (size_t)(m0 + row) * 1024 + k0 + ((u ^ (row & 7)) << 2),
               AsD + ((i * 256 + wave * 64) << 2));
    }
#pragma unroll
    for (int i = 0; i < 2; ++i) {  // W bf16 rows 64B: swz u^((row>>1)&3)
      int g = i * 256 + tid;
      int row = g >> 2, u = g & 3;
      ld_lds16(W + (size_t)(n0 + row) * 1024 + k0 + ((u ^ ((row >> 1) & 3)) << 3),
               BsD + ((i * 256 + wave * 64) << 3));
    }
  };

  auto round = [&](const float* AsC, const unsigned short* BsC, int nkt,
                   float* AsN, unsigned short* BsN) {
    bf16x8 af[4], bfr[4];
#pragma unroll
    for (int x = 0; x < 4; ++x) {
      int row = wm + x * 16 + (lane & 15);
      int swz = row & 7;
      f32x4 a0 = *(const f32x4*)(AsC + row * 32 + (((hi2 * 2) ^ swz) << 2));
      f32x4 a1 = *(const f32x4*)(AsC + row * 32 + (((hi2 * 2 + 1) ^ swz) << 2));
      union { u32x4 u; bf16x8 v; } f;
      f.u.x = cvtpk(a0.x, a0.y); f.u.y = cvtpk(a0.z, a0.w);
      f.u.z = cvtpk(a1.x, a1.y); f.u.w = cvtpk(a1.z, a1.w);
      af[x] = f.v;
      int brow = wn + x * 16 + (lane & 15);
      bfr[x] = *(const bf16x8*)(BsC + brow * 32 + ((hi2 ^ ((brow >> 1) & 3)) << 3));
    }
    if (nkt < 32) stage(AsN, BsN, nkt);  // prefetch flies under MFMA
#pragma unroll
    for (int mi = 0; mi < 4; ++mi)
#pragma unroll
      for (int ni = 0; ni < 4; ++ni)
        acc[mi][ni] = __builtin_amdgcn_mfma_f32_16x16x32_bf16(af[mi], bfr[ni], acc[mi][ni], 0, 0, 0);
    asm volatile("s_waitcnt vmcnt(0)" ::: "memory");
    __builtin_amdgcn_s_barrier();
  };

  stage(As0, Bs0, 0);
  asm volatile("s_waitcnt vmcnt(0)" ::: "memory");
  __builtin_amdgcn_s_barrier();

  for (int kt = 0; kt < 32; kt += 2) {
    round(As0, Bs0, kt + 1, As1, Bs1);
    round(As1, Bs1, kt + 2, As0, Bs0);
  }

  const int b = m0 >> 11;
  const int sbase = (m0 & 2047) + wm + ((lane >> 4) << 2);

  if (mat < 2) {  // Q/K: RoPE + bf16 store [bh][s][d]; Q also scaled by (1/8)*log2e
    unsigned short* dst = mat == 0 ? Qh : Kh;
    const float scale = mat == 0 ? 0.18033688011112042f : 1.0f;
#pragma unroll
    for (int ni = 0; ni < 4; ++ni) {
      int n = n0 + wn + ni * 16 + (lane & 15);
      int h = n >> 6, d = n & 63, fi = d >> 1;
      size_t base = (size_t)(b * 16 + h) * 131072 + d;
#pragma unroll
      for (int mi = 0; mi < 4; ++mi) {
#pragma unroll
        for (int r = 0; r < 4; ++r) {
          int s = sbase + mi * 16 + r;
          float v = acc[mi][ni][r];
          float p = __shfl_xor(v, 1);
          float c = cosT[(s << 5) + fi], sn = sinT[(s << 5) + fi];
          float ov = (d & 1) ? (p * sn + v * c) : (v * c - p * sn);
          dst[base + (size_t)s * 64] = f2bf(ov * scale);
        }
      }
    }
  } else {  // V: transposed bf16 store Vt [bh][d][s]
#pragma unroll
    for (int ni = 0; ni < 4; ++ni) {
      int n = n0 + wn + ni * 16 + (lane & 15);
      int h = n >> 6, d = n & 63;
#pragma unroll
      for (int mi = 0; mi < 4; ++mi) {
        u16x4 pk;
        pk.x = f2bf(acc[mi][ni][0]); pk.y = f2bf(acc[mi][ni][1]);
        pk.z = f2bf(acc[mi][ni][2]); pk.w = f2bf(acc[mi][ni][3]);
        int s = sbase + mi * 16;
        *(u16x4*)(Vt + ((size_t)(b * 16 + h) * 64 + d) * 2048 + s) = pk;
      }
    }
  }
}

// ---------------- Wo GEMM, STATIC double-buffer: A bf16, out f32 + bias ----------------
// Same recipe as gemm_qkv (verified twice): reads(cur) -> stage(other) -> MFMA ->
// vmcnt(0)+barrier. 32 KB LDS, VGPR ~104.
__global__ __launch_bounds__(256) void gemm_wo(const unsigned short* __restrict__ Ab,
                                               const unsigned short* __restrict__ W,
                                               float* __restrict__ outp,
                                               const float* __restrict__ bo) {
  __shared__ __align__(16) unsigned short As0[128 * 32];
  __shared__ __align__(16) unsigned short As1[128 * 32];
  __shared__ __align__(16) unsigned short Bs0[128 * 32];
  __shared__ __align__(16) unsigned short Bs1[128 * 32];

  const int tid = threadIdx.x;
  const int lane = tid & 63;
  const int wave = tid >> 6;
  const int flat = blockIdx.x;
  const int wgid = (flat & 7) * 64 + (flat >> 3);
  const int m0 = (wgid >> 3) * 128;
  const int n0 = (wgid & 7) * 128;
  const int wm = (wave >> 1) * 64;
  const int wn = (wave & 1) * 64;
  const int hi2 = lane >> 4;

  f32x4 acc[4][4] = {};

  auto stage = [&](unsigned short* AsD, unsigned short* BsD, int kt) {
    const int k0 = kt * 32;
#pragma unroll
    for (int i = 0; i < 2; ++i) {  // bf16 rows 64B: swz u^((row>>1)&3)
      int g = i * 256 + tid;
      int row = g >> 2, u = g & 3;
      ld_lds16(Ab + (size_t)(m0 + row) * 1024 + k0 + ((u ^ ((row >> 1) & 3)) << 3),
               AsD + ((i * 256 + wave * 64) << 3));
      ld_lds16(W + (size_t)(n0 + row) * 1024 + k0 + ((u ^ ((row >> 1) & 3)) << 3),
               BsD + ((i * 256 + wave * 64) << 3));
    }
  };

  auto round = [&](const unsigned short* AsC, const unsigned short* BsC, int nkt,
                   unsigned short* AsN, unsigned short* BsN) {
    bf16x8 af[4], bfr[4];
#pragma unroll
    for (int x = 0; x < 4; ++x) {
      int row = wm + x * 16 + (lane & 15);
      af[x] = *(const bf16x8*)(AsC + row * 32 + ((hi2 ^ ((row >> 1) & 3)) << 3));
      int brow = wn + x * 16 + (lane & 15);
      bfr[x] = *(const bf16x8*)(BsC + brow * 32 + ((hi2 ^ ((brow >> 1) & 3)) << 3));
    }
    if (nkt < 32) stage(AsN, BsN, nkt);
#pragma unroll
    for (int mi = 0; mi < 4; ++mi)
#pragma unroll
      for (int ni = 0; ni < 4; ++ni)
        acc[mi][ni] = __builtin_amdgcn_mfma_f32_16x16x32_bf16(af[mi], bfr[ni], acc[mi][ni], 0, 0, 0);
    asm volatile("s_waitcnt vmcnt(0)" ::: "memory");
    __builtin_amdgcn_s_barrier();
  };

  stage(As0, Bs0, 0);
  asm volatile("s_waitcnt vmcnt(0)" ::: "memory");
  __builtin_amdgcn_s_barrier();

  for (int kt = 0; kt < 32; kt += 2) {
    round(As0, Bs0, kt + 1, As1, Bs1);
    round(As1, Bs1, kt + 2, As0, Bs0);
  }

#pragma unroll
  for (int ni = 0; ni < 4; ++ni) {
    int n = n0 + wn + ni * 16 + (lane & 15);
    float bias = bo[n];
#pragma unroll
    for (int mi = 0; mi < 4; ++mi)
#pragma unroll
      for (int r = 0; r < 4; ++r) {
        int m = m0 + wm + mi * 16 + ((lane >> 4) << 2) + r;
        outp[(size_t)m * 1024 + n] = acc[mi][ni][r] + bias;
      }
  }
}

// exp2 + sum + pack one 64-key S^T pair -> PV A-fragments; returns lane-partial sum
DEVI float tile_sm(f32x16& s0, f32x16& s1, bf16x8* pa) {
  float a0 = 0.f, a1 = 0.f, a2 = 0.f, a3 = 0.f;
#pragma unroll
  for (int r = 0; r < 16; r += 4) {
    s0[r] = __builtin_amdgcn_exp2f(s0[r]);         a0 += s0[r];
    s0[r + 1] = __builtin_amdgcn_exp2f(s0[r + 1]); a1 += s0[r + 1];
    s0[r + 2] = __builtin_amdgcn_exp2f(s0[r + 2]); a2 += s0[r + 2];
    s0[r + 3] = __builtin_amdgcn_exp2f(s0[r + 3]); a3 += s0[r + 3];
  }
#pragma unroll
  for (int r = 0; r < 16; r += 4) {
    s1[r] = __builtin_amdgcn_exp2f(s1[r]);         a0 += s1[r];
    s1[r + 1] = __builtin_amdgcn_exp2f(s1[r + 1]); a1 += s1[r + 1];
    s1[r + 2] = __builtin_amdgcn_exp2f(s1[r + 2]); a2 += s1[r + 2];
    s1[r + 3] = __builtin_amdgcn_exp2f(s1[r + 3]); a3 += s1[r + 3];
  }
#pragma unroll
  for (int blk = 0; blk < 2; ++blk) {
    const f32x16& s = blk ? s1 : s0;
#pragma unroll
    for (int half = 0; half < 2; ++half) {
      int o = half * 8;
      unsigned u0 = cvtpk(s[o + 0], s[o + 1]);
      unsigned u1 = cvtpk(s[o + 2], s[o + 3]);
      unsigned u2 = cvtpk(s[o + 4], s[o + 5]);
      unsigned u3 = cvtpk(s[o + 6], s[o + 7]);
      auto r02 = __builtin_amdgcn_permlane32_swap(u0, u2, false, false);
      auto r13 = __builtin_amdgcn_permlane32_swap(u1, u3, false, false);
      union { u32x4 u; bf16x8 v; } f;
      f.u.x = r02[0]; f.u.y = r13[0]; f.u.z = r02[1]; f.u.w = r13[1];
      pa[blk * 2 + half] = f.v;
    }
  }
  return (a0 + a1) + (a2 + a3);
}

// ---------------- flash attention: KVBLK=64, 64 q/wave, race-free two-barrier rounds (R17) ----------------
__global__ __launch_bounds__(256, 2) void attn_kernel(const unsigned short* __restrict__ Qh,
                                                      const unsigned short* __restrict__ Kh,
                                                      const unsigned short* __restrict__ Vt,
                                                      unsigned short* __restrict__ AOb) {
  __shared__ __align__(16) unsigned short SM[4][4096];  // K0,V0,K1,V1

  const int tid = threadIdx.x, lane = tid & 63, wave = tid >> 6;
  const int lid = blockIdx.x;  // 0..511
  const int xcd = lid & 7, slot = lid >> 3;
  const int bh = xcd * 8 + (slot >> 3);  // 8 bh per XCD
  const int qb = slot & 7;
  const int q0 = qb * 256 + wave * 64;
  const int lq = lane & 31, hi = lane >> 5;

  const unsigned short* Qgb = Qh + (size_t)bh * 131072;
  const unsigned short* Kgb = Kh + (size_t)bh * 131072;
  const unsigned short* Vgb = Vt + (size_t)bh * 131072;

  bf16x8 qfa[4], qfb[4];
#pragma unroll
  for (int st = 0; st < 4; ++st) {
    qfa[st] = *(const bf16x8*)(Qgb + (size_t)(q0 + lq) * 64 + st * 16 + hi * 8);
    qfb[st] = *(const bf16x8*)(Qgb + (size_t)(q0 + 32 + lq) * 64 + st * 16 + hi * 8);
  }

  const int r0 = wave * 8 + (lane >> 3);
  const int u0 = lane & 7;
  const int sw = (u0 ^ (r0 & 7)) << 3;
  const unsigned short* kp0 = Kgb + r0 * 64 + sw;
  const unsigned short* kp1 = Kgb + (32 + r0) * 64 + sw;
  const unsigned short* vp0 = Vgb + (size_t)r0 * 2048 + sw;
  const unsigned short* vp1 = Vgb + (size_t)(32 + r0) * 2048 + sw;
  const int d0 = wave * 512, d1 = 2048 + wave * 512;

  auto stage = [&](int buf, int kt) {
    unsigned short* Kd = SM[buf * 2];
    unsigned short* Vd = SM[buf * 2 + 1];
    ld_lds16(kp0 + kt * 4096, Kd + d0);
    ld_lds16(kp1 + kt * 4096, Kd + d1);
    ld_lds16(vp0 + kt * 64, Vd + d0);
    ld_lds16(vp1 + kt * 64, Vd + d1);
  };
  auto frag = [&](const unsigned short* base, int row, int c) -> bf16x8 {
    return *(const bf16x8*)(base + row * 64 + (((c ^ (row & 7)) << 3)));
  };

  f32x16 o0a = {}, o1a = {}, o0b = {}, o1b = {};
  float lsA = 0.f, lsB = 0.f;

  stage(0, 0);

  for (int kt = 0; kt < 32; ++kt) {
    const int cur = kt & 1;
    if (kt < 31) {
      stage(cur ^ 1, kt + 1);
      asm volatile("s_waitcnt vmcnt(4)" ::: "memory");  // tile kt landed; kt+1 in flight
    } else {
      asm volatile("s_waitcnt vmcnt(0)" ::: "memory");
    }
    __builtin_amdgcn_s_barrier();  // barrier1: all waves' tile-kt DMA visible
    const unsigned short* Kc = SM[cur * 2];
    const unsigned short* Vc = SM[cur * 2 + 1];

    // all frag reads up front: V-read latency hides under QK+SM
    bf16x8 kf0[4], kf1[4], vf0[4], vf1[4];
#pragma unroll
    for (int st = 0; st < 4; ++st) {
      kf0[st] = frag(Kc, lq, st * 2 + hi);
      kf1[st] = frag(Kc, 32 + lq, st * 2 + hi);
      vf0[st] = frag(Vc, lq, st * 2 + hi);
      vf1[st] = frag(Vc, 32 + lq, st * 2 + hi);
    }

    f32x16 s0a = {}, s1a = {}, s0b = {}, s1b = {};
#pragma unroll
    for (int st = 0; st < 4; ++st) {
      s0a = __builtin_amdgcn_mfma_f32_32x32x16_bf16(kf0[st], qfa[st], s0a, 0, 0, 0);
      s1a = __builtin_amdgcn_mfma_f32_32x32x16_bf16(kf1[st], qfa[st], s1a, 0, 0, 0);
      s0b = __builtin_amdgcn_mfma_f32_32x32x16_bf16(kf0[st], qfb[st], s0b, 0, 0, 0);
      s1b = __builtin_amdgcn_mfma_f32_32x32x16_bf16(kf1[st], qfb[st], s1b, 0, 0, 0);
    }

    bf16x8 paA[4], paB[4];
    lsA += tile_sm(s0a, s1a, paA);
    lsB += tile_sm(s0b, s1b, paB);

#pragma unroll
    for (int kc = 0; kc < 4; ++kc) {
      o0a = __builtin_amdgcn_mfma_f32_32x32x16_bf16(paA[kc], vf0[kc], o0a, 0, 0, 0);
      o1a = __builtin_amdgcn_mfma_f32_32x32x16_bf16(paA[kc], vf1[kc], o1a, 0, 0, 0);
      o0b = __builtin_amdgcn_mfma_f32_32x32x16_bf16(paB[kc], vf0[kc], o0b, 0, 0, 0);
      o1b = __builtin_amdgcn_mfma_f32_32x32x16_bf16(paB[kc], vf1[kc], o1b, 0, 0, 0);
    }

    if (kt < 31) {
      __builtin_amdgcn_s_barrier();  // barrier2: reads of cur done before next round's
    }                                // stage overwrites it (WAR fix)
  }

  lsA += __shfl_xor(lsA, 32);
  lsB += __shfl_xor(lsB, 32);
  const int b = bh >> 4, h = bh & 15;
#pragma unroll
  for (int r = 0; r < 16; ++r) {
    int row = (r & 3) + 8 * (r >> 2) + 4 * hi;
    float ia = 1.0f / __shfl(lsA, row);
    float ib = 1.0f / __shfl(lsB, row);
    unsigned short* da = AOb + (size_t)(b * 2048 + q0 + row) * 1024 + h * 64;
    unsigned short* db = AOb + (size_t)(b * 2048 + q0 + 32 + row) * 1024 + h * 64;
    da[lq] = f2bf(o0a[r] * ia);
    da[32 + lq] = f2bf(o1a[r] * ia);
    db[lq] = f2bf(o0b[r] * ib);
    db[32 + lq] = f2bf(o1b[r] * ib);
  }
}

extern "C" void kernel_launch(void* const* d_in, const int* in_sizes, int n_in,
                              void* d_out, int out_size, void* d_ws, size_t ws_size,
                              hipStream_t stream) {
  const float* query = (const float*)d_in[0];
  const float* key = (const float*)d_in[1];
  const float* value = (const float*)d_in[2];
  const float* Wq = (const float*)d_in[3];
  const float* Wk = (const float*)d_in[4];
  const float* Wv = (const float*)d_in[5];
  const float* Wo = (const float*)d_in[6];
  const float* bo = (const float*)d_in[7];

  char* ws = (char*)d_ws;
  unsigned short* Wb = (unsigned short*)(ws + WS_WB);
  float* cosT = (float*)(ws + WS_COS);
  float* sinT = (float*)(ws + WS_SIN);
  unsigned short* Qh = (unsigned short*)(ws + WS_QH);
  unsigned short* Kh = (unsigned short*)(ws + WS_KH);
  unsigned short* Vt = (unsigned short*)(ws + WS_VT);
  unsigned short* AOb = (unsigned short*)(ws + WS_AO);

  prep<<<dim3(1024, 5), 256, 0, stream>>>(Wq, Wk, Wv, Wo, Wb, cosT, sinT);
  gemm_qkv<<<dim3(512, 3), 256, 0, stream>>>(query, key, value, Wb, Qh, Kh, Vt, cosT, sinT);
  attn_kernel<<<512, 256, 0, stream>>>(Qh, Kh, Vt, AOb);
  gemm_wo<<<512, 256, 0, stream>>>(AOb, Wb + 3145728, (float*)d_out, bo);
}

// Round 19
// 203.780 us; speedup vs baseline: 1.2126x; 1.0038x over previous
//
#include <hip/hip_runtime.h>
#include <math.h>

typedef __attribute__((ext_vector_type(4))) float f32x4;
typedef __attribute__((ext_vector_type(16))) float f32x16;
typedef __attribute__((ext_vector_type(8))) __bf16 bf16x8;
typedef __attribute__((ext_vector_type(4))) unsigned int u32x4;
typedef __attribute__((ext_vector_type(4))) unsigned short u16x4;

#define DEVI __device__ __forceinline__

// B=4, S=2048, E=1024, H=16, D=64, M=B*S=8192
constexpr size_t WS_WB  = 0;
constexpr size_t WS_COS = 4ull * 1024 * 1024 * 2;
constexpr size_t WS_SIN = WS_COS + 2048 * 32 * 4;
constexpr size_t WS_QH  = WS_SIN + 2048 * 32 * 4;
constexpr size_t WS_KH  = WS_QH + 64ull * 2048 * 64 * 2;
constexpr size_t WS_VT  = WS_KH + 64ull * 2048 * 64 * 2;
constexpr size_t WS_AO  = WS_VT + 64ull * 64 * 2048 * 2;  // AO bf16 [8192][1024]

DEVI unsigned short f2bf(float x) {
  union { float f; unsigned int u; } v; v.f = x;
  unsigned int r = v.u + 0x7fffu + ((v.u >> 16) & 1u);  // RNE
  return (unsigned short)(r >> 16);
}

DEVI unsigned cvtpk(float a, float b) {
  union { __bf16 h[2]; unsigned u; } x;
  x.h[0] = (__bf16)a; x.h[1] = (__bf16)b;
  return x.u;
}

// async global->LDS DMA, 16B/lane; dest = wave-uniform base, HW adds lane*16
DEVI void ld_lds16(const void* g, void* l) {
  __builtin_amdgcn_global_load_lds((const __attribute__((address_space(1))) void*)g,
                                   (__attribute__((address_space(3))) void*)l, 16, 0, 0);
}

// ---------------- prep: weights fp32->bf16 (y<4) + RoPE tables (y==4) ----------------
__global__ __launch_bounds__(256) void prep(const float* __restrict__ w0,
                                            const float* __restrict__ w1,
                                            const float* __restrict__ w2,
                                            const float* __restrict__ w3,
                                            unsigned short* __restrict__ out,
                                            float* __restrict__ cosT,
                                            float* __restrict__ sinT) {
  if (blockIdx.y == 4) {
    if (blockIdx.x >= 256) return;
    int idx = blockIdx.x * 256 + threadIdx.x;  // 65536 = 2048*32
    int s = idx >> 5, i = idx & 31;
    double ang = (double)s * pow(10000.0, -(double)i / 32.0);
    cosT[idx] = (float)cos(ang);
    sinT[idx] = (float)sin(ang);
    return;
  }
  const float* w = blockIdx.y == 0 ? w0 : blockIdx.y == 1 ? w1 : blockIdx.y == 2 ? w2 : w3;
  int i = (blockIdx.x * 256 + threadIdx.x) * 4;
  f32x4 v = *(const f32x4*)(w + i);
  u16x4 o;
  o.x = f2bf(v.x); o.y = f2bf(v.y); o.z = f2bf(v.z); o.w = f2bf(v.w);
  *(u16x4*)(out + (size_t)blockIdx.y * 1048576 + i) = o;
}

// ---------------- merged QKV GEMM, STATIC double-buffer: grid (512, 3) (R17-proven) ----------------
__global__ __launch_bounds__(256) void gemm_qkv(const float* __restrict__ Aq,
                                                const float* __restrict__ Ak,
                                                const float* __restrict__ Av,
                                                const unsigned short* __restrict__ Wb,
                                                unsigned short* __restrict__ Qh,
                                                unsigned short* __restrict__ Kh,
                                                unsigned short* __restrict__ Vt,
                                                const float* __restrict__ cosT,
                                                const float* __restrict__ sinT) {
  __shared__ __align__(16) float As0[128 * 32];            // [128][32] f32
  __shared__ __align__(16) float As1[128 * 32];
  __shared__ __align__(16) unsigned short Bs0[128 * 32];   // [128][32] bf16
  __shared__ __align__(16) unsigned short Bs1[128 * 32];

  const int mat = blockIdx.y;  // 0=Q 1=K 2=V
  const float* A = mat == 0 ? Aq : mat == 1 ? Ak : Av;
  const unsigned short* W = Wb + (size_t)mat * 1048576;

  const int tid = threadIdx.x;
  const int lane = tid & 63;
  const int wave = tid >> 6;
  const int flat = blockIdx.x;
  const int wgid = (flat & 7) * 64 + (flat >> 3);  // XCD chunk-swizzle
  const int m0 = (wgid >> 3) * 128;
  const int n0 = (wgid & 7) * 128;
  const int wm = (wave >> 1) * 64;
  const int wn = (wave & 1) * 64;
  const int hi2 = lane >> 4;

  f32x4 acc[4][4] = {};

  auto stage = [&](float* AsD, unsigned short* BsD, int kt) {
    const int k0 = kt * 32;
#pragma unroll
    for (int i = 0; i < 4; ++i) {  // A f32 rows 128B: swz u^(row&7) on 16B units
      int g = i * 256 + tid;
      int row = g >> 3, u = g & 7;
      ld_lds16(A + (size_t)(m0 + row) * 1024 + k0 + ((u ^ (row & 7)) << 2),
               AsD + ((i * 256 + wave * 64) << 2));
    }
#pragma unroll
    for (int i = 0; i < 2; ++i) {  // W bf16 rows 64B: swz u^((row>>1)&3)
      int g = i * 256 + tid;
      int row = g >> 2, u = g & 3;
      ld_lds16(W + (size_t)(n0 + row) * 1024 + k0 + ((u ^ ((row >> 1) & 3)) << 3),
               BsD + ((i * 256 + wave * 64) << 3));
    }
  };

  auto round = [&](const float* AsC, const unsigned short* BsC, int nkt,
                   float* AsN, unsigned short* BsN) {
    bf16x8 af[4], bfr[4];
#pragma unroll
    for (int x = 0; x < 4; ++x) {
      int row = wm + x * 16 + (lane & 15);
      int swz = row & 7;
      f32x4 a0 = *(const f32x4*)(AsC + row * 32 + (((hi2 * 2) ^ swz) << 2));
      f32x4 a1 = *(const f32x4*)(AsC + row * 32 + (((hi2 * 2 + 1) ^ swz) << 2));
      union { u32x4 u; bf16x8 v; } f;
      f.u.x = cvtpk(a0.x, a0.y); f.u.y = cvtpk(a0.z, a0.w);
      f.u.z = cvtpk(a1.x, a1.y); f.u.w = cvtpk(a1.z, a1.w);
      af[x] = f.v;
      int brow = wn + x * 16 + (lane & 15);
      bfr[x] = *(const bf16x8*)(BsC + brow * 32 + ((hi2 ^ ((brow >> 1) & 3)) << 3));
    }
    if (nkt < 32) stage(AsN, BsN, nkt);  // prefetch flies under MFMA
#pragma unroll
    for (int mi = 0; mi < 4; ++mi)
#pragma unroll
      for (int ni = 0; ni < 4; ++ni)
        acc[mi][ni] = __builtin_amdgcn_mfma_f32_16x16x32_bf16(af[mi], bfr[ni], acc[mi][ni], 0, 0, 0);
    asm volatile("s_waitcnt vmcnt(0)" ::: "memory");
    __builtin_amdgcn_s_barrier();
  };

  stage(As0, Bs0, 0);
  asm volatile("s_waitcnt vmcnt(0)" ::: "memory");
  __builtin_amdgcn_s_barrier();

  for (int kt = 0; kt < 32; kt += 2) {
    round(As0, Bs0, kt + 1, As1, Bs1);
    round(As1, Bs1, kt + 2, As0, Bs0);
  }

  const int b = m0 >> 11;
  const int sbase = (m0 & 2047) + wm + ((lane >> 4) << 2);

  if (mat < 2) {  // Q/K: RoPE + bf16 store [bh][s][d]; Q also scaled by (1/8)*log2e
    unsigned short* dst = mat == 0 ? Qh : Kh;
    const float scale = mat == 0 ? 0.18033688011112042f : 1.0f;
#pragma unroll
    for (int ni = 0; ni < 4; ++ni) {
      int n = n0 + wn + ni * 16 + (lane & 15);
      int h = n >> 6, d = n & 63, fi = d >> 1;
      size_t base = (size_t)(b * 16 + h) * 131072 + d;
#pragma unroll
      for (int mi = 0; mi < 4; ++mi) {
#pragma unroll
        for (int r = 0; r < 4; ++r) {
          int s = sbase + mi * 16 + r;
          float v = acc[mi][ni][r];
          float p = __shfl_xor(v, 1);
          float c = cosT[(s << 5) + fi], sn = sinT[(s << 5) + fi];
          float ov = (d & 1) ? (p * sn + v * c) : (v * c - p * sn);
          dst[base + (size_t)s * 64] = f2bf(ov * scale);
        }
      }
    }
  } else {  // V: transposed bf16 store Vt [bh][d][s]
#pragma unroll
    for (int ni = 0; ni < 4; ++ni) {
      int n = n0 + wn + ni * 16 + (lane & 15);
      int h = n >> 6, d = n & 63;
#pragma unroll
      for (int mi = 0; mi < 4; ++mi) {
        u16x4 pk;
        pk.x = f2bf(acc[mi][ni][0]); pk.y = f2bf(acc[mi][ni][1]);
        pk.z = f2bf(acc[mi][ni][2]); pk.w = f2bf(acc[mi][ni][3]);
        int s = sbase + mi * 16;
        *(u16x4*)(Vt + ((size_t)(b * 16 + h) * 64 + d) * 2048 + s) = pk;
      }
    }
  }
}

// ---------------- Wo GEMM, STATIC double-buffer: A bf16, out f32 + bias ----------------
// Same recipe as gemm_qkv (verified twice): reads(cur) -> stage(other) -> MFMA ->
// vmcnt(0)+barrier. 32 KB LDS, VGPR ~104.
__global__ __launch_bounds__(256) void gemm_wo(const unsigned short* __restrict__ Ab,
                                               const unsigned short* __restrict__ W,
                                               float* __restrict__ outp,
                                               const float* __restrict__ bo) {
  __shared__ __align__(16) unsigned short As0[128 * 32];
  __shared__ __align__(16) unsigned short As1[128 * 32];
  __shared__ __align__(16) unsigned short Bs0[128 * 32];
  __shared__ __align__(16) unsigned short Bs1[128 * 32];

  const int tid = threadIdx.x;
  const int lane = tid & 63;
  const int wave = tid >> 6;
  const int flat = blockIdx.x;
  const int wgid = (flat & 7) * 64 + (flat >> 3);
  const int m0 = (wgid >> 3) * 128;
  const int n0 = (wgid & 7) * 128;
  const int wm = (wave >> 1) * 64;
  const int wn = (wave & 1) * 64;
  const int hi2 = lane >> 4;

  f32x4 acc[4][4] = {};

  auto stage = [&](unsigned short* AsD, unsigned short* BsD, int kt) {
    const int k0 = kt * 32;
#pragma unroll
    for (int i = 0; i < 2; ++i) {  // bf16 rows 64B: swz u^((row>>1)&3)
      int g = i * 256 + tid;
      int row = g >> 2, u = g & 3;
      ld_lds16(Ab + (size_t)(m0 + row) * 1024 + k0 + ((u ^ ((row >> 1) & 3)) << 3),
               AsD + ((i * 256 + wave * 64) << 3));
      ld_lds16(W + (size_t)(n0 + row) * 1024 + k0 + ((u ^ ((row >> 1) & 3)) << 3),
               BsD + ((i * 256 + wave * 64) << 3));
    }
  };

  auto round = [&](const unsigned short* AsC, const unsigned short* BsC, int nkt,
                   unsigned short* AsN, unsigned short* BsN) {
    bf16x8 af[4], bfr[4];
#pragma unroll
    for (int x = 0; x < 4; ++x) {
      int row = wm + x * 16 + (lane & 15);
      af[x] = *(const bf16x8*)(AsC + row * 32 + ((hi2 ^ ((row >> 1) & 3)) << 3));
      int brow = wn + x * 16 + (lane & 15);
      bfr[x] = *(const bf16x8*)(BsC + brow * 32 + ((hi2 ^ ((brow >> 1) & 3)) << 3));
    }
    if (nkt < 32) stage(AsN, BsN, nkt);
#pragma unroll
    for (int mi = 0; mi < 4; ++mi)
#pragma unroll
      for (int ni = 0; ni < 4; ++ni)
        acc[mi][ni] = __builtin_amdgcn_mfma_f32_16x16x32_bf16(af[mi], bfr[ni], acc[mi][ni], 0, 0, 0);
    asm volatile("s_waitcnt vmcnt(0)" ::: "memory");
    __builtin_amdgcn_s_barrier();
  };

  stage(As0, Bs0, 0);
  asm volatile("s_waitcnt vmcnt(0)" ::: "memory");
  __builtin_amdgcn_s_barrier();

  for (int kt = 0; kt < 32; kt += 2) {
    round(As0, Bs0, kt + 1, As1, Bs1);
    round(As1, Bs1, kt + 2, As0, Bs0);
  }

#pragma unroll
  for (int ni = 0; ni < 4; ++ni) {
    int n = n0 + wn + ni * 16 + (lane & 15);
    float bias = bo[n];
#pragma unroll
    for (int mi = 0; mi < 4; ++mi)
#pragma unroll
      for (int r = 0; r < 4; ++r) {
        int m = m0 + wm + mi * 16 + ((lane >> 4) << 2) + r;
        outp[(size_t)m * 1024 + n] = acc[mi][ni][r] + bias;
      }
  }
}

// exp2 + sum + pack one 64-key S^T pair -> PV A-fragments; returns lane-partial sum
DEVI float tile_sm(f32x16& s0, f32x16& s1, bf16x8* pa) {
  float a0 = 0.f, a1 = 0.f, a2 = 0.f, a3 = 0.f;
#pragma unroll
  for (int r = 0; r < 16; r += 4) {
    s0[r] = __builtin_amdgcn_exp2f(s0[r]);         a0 += s0[r];
    s0[r + 1] = __builtin_amdgcn_exp2f(s0[r + 1]); a1 += s0[r + 1];
    s0[r + 2] = __builtin_amdgcn_exp2f(s0[r + 2]); a2 += s0[r + 2];
    s0[r + 3] = __builtin_amdgcn_exp2f(s0[r + 3]); a3 += s0[r + 3];
  }
#pragma unroll
  for (int r = 0; r < 16; r += 4) {
    s1[r] = __builtin_amdgcn_exp2f(s1[r]);         a0 += s1[r];
    s1[r + 1] = __builtin_amdgcn_exp2f(s1[r + 1]); a1 += s1[r + 1];
    s1[r + 2] = __builtin_amdgcn_exp2f(s1[r + 2]); a2 += s1[r + 2];
    s1[r + 3] = __builtin_amdgcn_exp2f(s1[r + 3]); a3 += s1[r + 3];
  }
#pragma unroll
  for (int blk = 0; blk < 2; ++blk) {
    const f32x16& s = blk ? s1 : s0;
#pragma unroll
    for (int half = 0; half < 2; ++half) {
      int o = half * 8;
      unsigned u0 = cvtpk(s[o + 0], s[o + 1]);
      unsigned u1 = cvtpk(s[o + 2], s[o + 3]);
      unsigned u2 = cvtpk(s[o + 4], s[o + 5]);
      unsigned u3 = cvtpk(s[o + 6], s[o + 7]);
      auto r02 = __builtin_amdgcn_permlane32_swap(u0, u2, false, false);
      auto r13 = __builtin_amdgcn_permlane32_swap(u1, u3, false, false);
      union { u32x4 u; bf16x8 v; } f;
      f.u.x = r02[0]; f.u.y = r13[0]; f.u.z = r02[1]; f.u.w = r13[1];
      pa[blk * 2 + half] = f.v;
    }
  }
  return (a0 + a1) + (a2 + a3);
}

// ---------------- flash attention: KVBLK=64, 64 q/wave, race-free two-barrier rounds (R17) ----------------
__global__ __launch_bounds__(256, 2) void attn_kernel(const unsigned short* __restrict__ Qh,
                                                      const unsigned short* __restrict__ Kh,
                                                      const unsigned short* __restrict__ Vt,
                                                      unsigned short* __restrict__ AOb) {
  __shared__ __align__(16) unsigned short SM[4][4096];  // K0,V0,K1,V1

  const int tid = threadIdx.x, lane = tid & 63, wave = tid >> 6;
  const int lid = blockIdx.x;  // 0..511
  const int xcd = lid & 7, slot = lid >> 3;
  const int bh = xcd * 8 + (slot >> 3);  // 8 bh per XCD
  const int qb = slot & 7;
  const int q0 = qb * 256 + wave * 64;
  const int lq = lane & 31, hi = lane >> 5;

  const unsigned short* Qgb = Qh + (size_t)bh * 131072;
  const unsigned short* Kgb = Kh + (size_t)bh * 131072;
  const unsigned short* Vgb = Vt + (size_t)bh * 131072;

  bf16x8 qfa[4], qfb[4];
#pragma unroll
  for (int st = 0; st < 4; ++st) {
    qfa[st] = *(const bf16x8*)(Qgb + (size_t)(q0 + lq) * 64 + st * 16 + hi * 8);
    qfb[st] = *(const bf16x8*)(Qgb + (size_t)(q0 + 32 + lq) * 64 + st * 16 + hi * 8);
  }

  const int r0 = wave * 8 + (lane >> 3);
  const int u0 = lane & 7;
  const int sw = (u0 ^ (r0 & 7)) << 3;
  const unsigned short* kp0 = Kgb + r0 * 64 + sw;
  const unsigned short* kp1 = Kgb + (32 + r0) * 64 + sw;
  const unsigned short* vp0 = Vgb + (size_t)r0 * 2048 + sw;
  const unsigned short* vp1 = Vgb + (size_t)(32 + r0) * 2048 + sw;
  const int d0 = wave * 512, d1 = 2048 + wave * 512;

  auto stage = [&](int buf, int kt) {
    unsigned short* Kd = SM[buf * 2];
    unsigned short* Vd = SM[buf * 2 + 1];
    ld_lds16(kp0 + kt * 4096, Kd + d0);
    ld_lds16(kp1 + kt * 4096, Kd + d1);
    ld_lds16(vp0 + kt * 64, Vd + d0);
    ld_lds16(vp1 + kt * 64, Vd + d1);
  };
  auto frag = [&](const unsigned short* base, int row, int c) -> bf16x8 {
    return *(const bf16x8*)(base + row * 64 + (((c ^ (row & 7)) << 3)));
  };

  f32x16 o0a = {}, o1a = {}, o0b = {}, o1b = {};
  float lsA = 0.f, lsB = 0.f;

  stage(0, 0);

  for (int kt = 0; kt < 32; ++kt) {
    const int cur = kt & 1;
    if (kt < 31) {
      stage(cur ^ 1, kt + 1);
      asm volatile("s_waitcnt vmcnt(4)" ::: "memory");  // tile kt landed; kt+1 in flight
    } else {
      asm volatile("s_waitcnt vmcnt(0)" ::: "memory");
    }
    __builtin_amdgcn_s_barrier();  // barrier1: all waves' tile-kt DMA visible
    const unsigned short* Kc = SM[cur * 2];
    const unsigned short* Vc = SM[cur * 2 + 1];

    // all frag reads up front: V-read latency hides under QK+SM
    bf16x8 kf0[4], kf1[4], vf0[4], vf1[4];
#pragma unroll
    for (int st = 0; st < 4; ++st) {
      kf0[st] = frag(Kc, lq, st * 2 + hi);
      kf1[st] = frag(Kc, 32 + lq, st * 2 + hi);
      vf0[st] = frag(Vc, lq, st * 2 + hi);
      vf1[st] = frag(Vc, 32 + lq, st * 2 + hi);
    }

    f32x16 s0a = {}, s1a = {}, s0b = {}, s1b = {};
#pragma unroll
    for (int st = 0; st < 4; ++st) {
      s0a = __builtin_amdgcn_mfma_f32_32x32x16_bf16(kf0[st], qfa[st], s0a, 0, 0, 0);
      s1a = __builtin_amdgcn_mfma_f32_32x32x16_bf16(kf1[st], qfa[st], s1a, 0, 0, 0);
      s0b = __builtin_amdgcn_mfma_f32_32x32x16_bf16(kf0[st], qfb[st], s0b, 0, 0, 0);
      s1b = __builtin_amdgcn_mfma_f32_32x32x16_bf16(kf1[st], qfb[st], s1b, 0, 0, 0);
    }

    bf16x8 paA[4], paB[4];
    lsA += tile_sm(s0a, s1a, paA);
    lsB += tile_sm(s0b, s1b, paB);

#pragma unroll
    for (int kc = 0; kc < 4; ++kc) {
      o0a = __builtin_amdgcn_mfma_f32_32x32x16_bf16(paA[kc], vf0[kc], o0a, 0, 0, 0);
      o1a = __builtin_amdgcn_mfma_f32_32x32x16_bf16(paA[kc], vf1[kc], o1a, 0, 0, 0);
      o0b = __builtin_amdgcn_mfma_f32_32x32x16_bf16(paB[kc], vf0[kc], o0b, 0, 0, 0);
      o1b = __builtin_amdgcn_mfma_f32_32x32x16_bf16(paB[kc], vf1[kc], o1b, 0, 0, 0);
    }

    if (kt < 31) {
      __builtin_amdgcn_s_barrier();  // barrier2: reads of cur done before next round's
    }                                // stage overwrites it (WAR fix)
  }

  lsA += __shfl_xor(lsA, 32);
  lsB += __shfl_xor(lsB, 32);
  const int b = bh >> 4, h = bh & 15;
#pragma unroll
  for (int r = 0; r < 16; ++r) {
    int row = (r & 3) + 8 * (r >> 2) + 4 * hi;
    float ia = 1.0f / __shfl(lsA, row);
    float ib = 1.0f / __shfl(lsB, row);
    unsigned short* da = AOb + (size_t)(b * 2048 + q0 + row) * 1024 + h * 64;
    unsigned short* db = AOb + (size_t)(b * 2048 + q0 + 32 + row) * 1024 + h * 64;
    da[lq] = f2bf(o0a[r] * ia);
    da[32 + lq] = f2bf(o1a[r] * ia);
    db[lq] = f2bf(o0b[r] * ib);
    db[32 + lq] = f2bf(o1b[r] * ib);
  }
}

extern "C" void kernel_launch(void* const* d_in, const int* in_sizes, int n_in,
                              void* d_out, int out_size, void* d_ws, size_t ws_size,
                              hipStream_t stream) {
  const float* query = (const float*)d_in[0];
  const float* key = (const float*)d_in[1];
  const float* value = (const float*)d_in[2];
  const float* Wq = (const float*)d_in[3];
  const float* Wk = (const float*)d_in[4];
  const float* Wv = (const float*)d_in[5];
  const float* Wo = (const float*)d_in[6];
  const float* bo = (const float*)d_in[7];

  char* ws = (char*)d_ws;
  unsigned short* Wb = (unsigned short*)(ws + WS_WB);
  float* cosT = (float*)(ws + WS_COS);
  float* sinT = (float*)(ws + WS_SIN);
  unsigned short* Qh = (unsigned short*)(ws + WS_QH);
  unsigned short* Kh = (unsigned short*)(ws + WS_KH);
  unsigned short* Vt = (unsigned short*)(ws + WS_VT);
  unsigned short* AOb = (unsigned short*)(ws + WS_AO);

  prep<<<dim3(1024, 5), 256, 0, stream>>>(Wq, Wk, Wv, Wo, Wb, cosT, sinT);
  gemm_qkv<<<dim3(512, 3), 256, 0, stream>>>(query, key, value, Wb, Qh, Kh, Vt, cosT, sinT);
  attn_kernel<<<512, 256, 0, stream>>>(Qh, Kh, Vt, AOb);
  gemm_wo<<<512, 256, 0, stream>>>(AOb, Wb + 3145728, (float*)d_out, bo);
}